// Round 12
// baseline (150.012 us; speedup 1.0000x reference)
//
#include <hip/hip_runtime.h>
#include <hip/hip_cooperative_groups.h>

// Fused MPNN layer, B=256, N=81, H=128, E=1620 — single cooperative kernel.
//   P = X @ Wm1[:H],  Q' = X @ Wm1[H:] + bm1
//   Hsum[t] = sum_{e: tgt=t} relu(P[src_e] + Q'[t])
//   Folded:  agg@Wu1b = (Hsum@Wc)*inv_deg + 1[deg>0]*bc,  Wc=Wm2@Wu1b, bc=bm2@Wu1b
//   h2 = relu(X@Wu1t + (Hsum@Wc)*inv + s*bc + bu1)
//   x  = X + h2 @ Wu2 + bu2 ;  out = LayerNorm(x)*gamma + beta
// Cooperative kernel, grid 256 x 1024 (1 block/CU, co-resident):
//   pre-sync: ALL blocks stage X->LDS; blocks 0-7 pack weights to fp16 frag
//   order in ws; block 8 ballot-CSR; blocks 9-12 Wc (fp16 WuL scratch) + bc.
//   grid.sync(); then the fp16 MFMA main pipeline (identical to r11).
// Fallback: two-kernel r11 path if cooperative launch unsupported.

#define NN 81
#define HH 128
#define EE 1620
#define NCHK 26                         // ceil(EE/64)
#define MPAD 96
#define WB_BYTES 196608                 // 6 * 16384 ushorts (slot4 unused)
#define OFFS_OFF (WB_BYTES)             // int offs[82]
#define CSR_OFF  (OFFS_OFF + 82 * 4)    // int csr[1620]
#define BC_OFF   (CSR_OFF + EE * 4)     // float bc[128]
#define WS_NEED  (BC_OFF + HH * 4)

// coop-kernel LDS arena (bytes)
#define CX_OFF    0                     // float X[81][128]      41472
#define CXB_OFF   41472                 // fp16 swz [96][128]    24576
#define CBP_OFF   66048                 // fp16 swz [96][128]    24576
#define CBQ_OFF   90624                 // fp16 swz [96][128]    24576
#define CCSR_OFF  115200                // int[1620]              6480
#define COFF_OFF  121680                // int[82]                 328
#define CBIAS_OFF 122008                // float[6][128]          3072
#define CL_BYTES  125080

typedef _Float16 f16x8 __attribute__((ext_vector_type(8)));
typedef __fp16   h16x2 __attribute__((ext_vector_type(2)));
typedef __attribute__((ext_vector_type(8))) unsigned short ushort8v;
typedef __attribute__((ext_vector_type(4))) float f32x4;

__device__ __forceinline__ unsigned short f2h(float f) {
  union { _Float16 h; unsigned short u; } v; v.h = (_Float16)f; return v.u;
}
__device__ __forceinline__ float h2f(unsigned short u) {
  union { unsigned short u; _Float16 h; } v; v.u = u; return (float)v.h;
}
__device__ __forceinline__ unsigned f2h2(float x, float y) {   // v_cvt_pkrtz
  union { h16x2 h; unsigned u; } v;
  v.h = __builtin_amdgcn_cvt_pkrtz(x, y);
  return v.u;
}
__device__ __forceinline__ unsigned pk_add(unsigned a, unsigned b) {
  unsigned r; asm("v_pk_add_f16 %0, %1, %2" : "=v"(r) : "v"(a), "v"(b)); return r;
}
__device__ __forceinline__ unsigned pk_relu(unsigned a) {
  unsigned r; asm("v_pk_max_f16 %0, %1, %2" : "=v"(r) : "v"(a), "v"(0u)); return r;
}
__device__ __forceinline__ unsigned swzu(int r, int laneb) {
  return ((unsigned)(r * 256 + laneb)) ^ ((unsigned)((r & 7) << 4));
}

// ---------------- MFMA helpers (fp16, per wave: 3 M-tiles x 1 N-tile) --------
__device__ __forceinline__ void loadB(const unsigned short* Wp, int nt0, int lane,
                                      f16x8 (&Bf)[4]) {
#pragma unroll
  for (int ks = 0; ks < 4; ++ks)
    Bf[ks] = *(const f16x8*)(Wp + ((nt0 * 4 + ks) * 64 + lane) * 8);
}

__device__ __forceinline__ void gemm3(const char* Ab, const f16x8 (&Bf)[4],
                                      int lane, int mt0, f32x4 (&acc)[3]) {
  const int rl = lane & 15;
  const int kb = (lane >> 4) * 16;
  const unsigned swz = (unsigned)((rl & 7) << 4);
#pragma unroll
  for (int ks = 0; ks < 4; ++ks)
#pragma unroll
    for (int mm = 0; mm < 3; ++mm) {
      const int r = (mt0 + mm) * 16 + rl;
      const unsigned byte = (unsigned)(r * 256) + (((unsigned)(ks * 64 + kb)) ^ swz);
      f16x8 a = *(const f16x8*)(Ab + byte);
      acc[mm] = __builtin_amdgcn_mfma_f32_16x16x32_f16(a, Bf[ks], acc[mm], 0, 0, 0);
    }
}

__device__ __forceinline__ void gemm3x2(const char* Ab,
                                        const f16x8 (&B0)[4], const f16x8 (&B1)[4],
                                        int lane, int mt0,
                                        f32x4 (&a0)[3], f32x4 (&a1)[3]) {
  const int rl = lane & 15;
  const int kb = (lane >> 4) * 16;
  const unsigned swz = (unsigned)((rl & 7) << 4);
#pragma unroll
  for (int ks = 0; ks < 4; ++ks)
#pragma unroll
    for (int mm = 0; mm < 3; ++mm) {
      const int r = (mt0 + mm) * 16 + rl;
      const unsigned byte = (unsigned)(r * 256) + (((unsigned)(ks * 64 + kb)) ^ swz);
      f16x8 a = *(const f16x8*)(Ab + byte);
      a0[mm] = __builtin_amdgcn_mfma_f32_16x16x32_f16(a, B0[ks], a0[mm], 0, 0, 0);
      a1[mm] = __builtin_amdgcn_mfma_f32_16x16x32_f16(a, B1[ks], a1[mm], 0, 0, 0);
    }
}

__device__ __forceinline__ void gemm3_2A(const char* A0, const char* A1,
                                         const f16x8 (&B0)[4], const f16x8 (&B1)[4],
                                         int lane, int mt0,
                                         f32x4 (&a0)[3], f32x4 (&a1)[3]) {
  const int rl = lane & 15;
  const int kb = (lane >> 4) * 16;
  const unsigned swz = (unsigned)((rl & 7) << 4);
#pragma unroll
  for (int ks = 0; ks < 4; ++ks)
#pragma unroll
    for (int mm = 0; mm < 3; ++mm) {
      const int r = (mt0 + mm) * 16 + rl;
      const unsigned byte = (unsigned)(r * 256) + (((unsigned)(ks * 64 + kb)) ^ swz);
      f16x8 x0 = *(const f16x8*)(A0 + byte);
      a0[mm] = __builtin_amdgcn_mfma_f32_16x16x32_f16(x0, B0[ks], a0[mm], 0, 0, 0);
      f16x8 x1 = *(const f16x8*)(A1 + byte);
      a1[mm] = __builtin_amdgcn_mfma_f32_16x16x32_f16(x1, B1[ks], a1[mm], 0, 0, 0);
    }
}

// =================== cooperative single kernel ===============================
__global__ __launch_bounds__(1024, 4)
void mpnn_coop_kernel(const float* node, const int* eidx,
                      const float* Wm1, const float* bm1,
                      const float* Wm2, const float* bm2,
                      const float* Wu1, const float* bu1,
                      const float* Wu2, const float* bu2,
                      const float* gamma_, const float* beta_,
                      char* ws, float* out) {
  __shared__ __align__(16) char L[CL_BYTES];
  float (*X)[HH] = (float(*)[HH])(L + CX_OFF);
  char* Xb   = L + CXB_OFF;
  char* bufP = L + CBP_OFF;
  char* bufQ = L + CBQ_OFF;
  int*  csrL = (int*)(L + CCSR_OFF);
  int*  offsL= (int*)(L + COFF_OFF);
  float (*bias)[HH] = (float(*)[HH])(L + CBIAS_OFF);

  const int tid  = threadIdx.x;
  const int lane = tid & 63;
  const int wave = tid >> 6;     // 0..15
  const int b    = blockIdx.x;

  // ---- pre-sync: stage X fp32 + Xb fp16 (swizzled) — ALL blocks ----
  {
    const float4* nf4 = (const float4*)(node + (size_t)b * NN * HH);
    const int i2 = tid + 2048;
    const bool has2 = (i2 < NN * HH / 4);     // 2592 float4 total
    float4 v0 = nf4[tid];
    float4 v1 = nf4[tid + 1024];
    float4 v2 = has2 ? nf4[i2] : make_float4(0.f, 0.f, 0.f, 0.f);
#pragma unroll
    for (int k = 0; k < 3; ++k) {
      const int i = tid + k * 1024;
      if (k == 2 && !has2) break;
      const float4 v = (k == 0) ? v0 : (k == 1) ? v1 : v2;
      const int r = i >> 5, c = (i & 31) * 4;
      *(float4*)&X[r][c] = v;
      uint2 pv; pv.x = f2h2(v.x, v.y); pv.y = f2h2(v.z, v.w);
      *(uint2*)(Xb + swzu(r, c * 2)) = pv;
    }
    if (tid < (MPAD - NN) * 16) {   // zero pad rows 81..95
      const int r = NN + tid / 16, m = tid % 16;
      ushort8v z = {0,0,0,0,0,0,0,0};
      *(ushort8v*)(Xb + swzu(r, m * 16)) = z;
    }
  }

  // ---- pre-sync setup roles ----
  if (b < 8) {
    // pack {Wm1t,Wm1b,Wu1t,Wu2} -> fp16 frag order in ws
    const int gid = b * 1024 + tid;
    const int ln = gid & 63;
    const int t = gid >> 6;                 // 0..127
    const int ks = t & 3, nt = (t >> 2) & 7, mat = t >> 5;
    const float* src;
    int slot;
    if (mat == 0)      { src = Wm1;           slot = 0; }
    else if (mat == 1) { src = Wm1 + HH * HH; slot = 1; }
    else if (mat == 2) { src = Wu1;           slot = 3; }
    else               { src = Wu2;           slot = 5; }
    const int c = nt * 16 + (ln & 15);
    const int k0 = ks * 32 + (ln >> 4) * 8;
    f16x8 pv;
#pragma unroll
    for (int j = 0; j < 8; ++j) pv[j] = (_Float16)src[(k0 + j) * HH + c];
    *(f16x8*)((unsigned short*)ws + (size_t)slot * 16384 + (((nt * 4 + ks) * 64) + ln) * 8) = pv;
  } else if (b == 8) {
    // deterministic CSR via ballot match-masks; scratch in bufP region
    int* srcE  = (int*)(L + CBP_OFF);    // EE
    int* tgtE  = srcE + EE;              // EE
    int* rankS = tgtE + EE;              // EE
    int* cntC  = rankS + EE;             // NCHK*NN
    int* tot   = cntC + NCHK * NN;       // NN
    int* scanS = tot + NN;               // 128
    int* wsumS = scanS + 128;            // 2
    int* offsS = wsumS + 2;              // NN+1
    for (int i = tid; i < NCHK * NN; i += 1024) cntC[i] = 0;
    for (int i = tid; i < 2 * EE; i += 1024) srcE[i] = eidx[i];
    __syncthreads();
    const int ln = tid & 63, wv = tid >> 6;
    for (int c = wv; c < NCHK; c += 16) {
      const int e = c * 64 + ln;
      const bool ok = (e < EE);
      const int t = ok ? tgtE[e] : -1;
      unsigned long long mymask = 0;
#pragma unroll
      for (int i = 0; i < 64; ++i) {
        const int ti = __shfl(t, i);
        const unsigned long long bal = __ballot(t == ti);
        if (i == ln) mymask = bal;
      }
      if (ok) {
        const int rank = __popcll(mymask & ((1ull << ln) - 1ull));
        rankS[e] = rank;
        if (rank == 0) cntC[c * NN + t] = __popcll(mymask);
      }
    }
    __syncthreads();
    if (tid < NN) {
      int s = 0;
#pragma unroll
      for (int c = 0; c < NCHK; ++c) s += cntC[c * NN + tid];
      tot[tid] = s;
    }
    __syncthreads();
    if (tid < 128) {
      const int l = tid & 63, w = tid >> 6;
      int inc = (tid < NN) ? tot[tid] : 0;
#pragma unroll
      for (int d = 1; d < 64; d <<= 1) {
        int u = __shfl_up(inc, d);
        if (l >= d) inc += u;
      }
      scanS[tid] = inc;
      if (l == 63) wsumS[w] = inc;
    }
    __syncthreads();
    if (tid < 128) {
      const int w = tid >> 6;
      const int inc = scanS[tid] + (w ? wsumS[0] : 0);
      if (tid < NN) offsS[tid] = inc - tot[tid];
      if (tid == NN - 1) offsS[NN] = inc;
    }
    __syncthreads();
    if (tid < NN) {
      int run = offsS[tid];
#pragma unroll
      for (int c = 0; c < NCHK; ++c) {
        const int tmp = cntC[c * NN + tid];
        cntC[c * NN + tid] = run;
        run += tmp;
      }
    }
    __syncthreads();
    int* wofs = (int*)(ws + OFFS_OFF);
    int* wcsr = (int*)(ws + CSR_OFF);
    for (int i = tid; i <= NN; i += 1024) wofs[i] = offsS[i];
    for (int e = tid; e < EE; e += 1024) {
      const int t = tgtE[e];
      wcsr[cntC[(e >> 6) * NN + t] + rankS[e]] = srcE[e];
    }
  } else if (b < 13) {
    // Wc = Wm2 @ Wu1b rows [32*bs,32*bs+32); fp16 WuL scratch in bufP/bufQ
    const int bs = b - 9;
    unsigned short* WuLh = (unsigned short*)(L + CBP_OFF);      // 32768 B
    float* WmL = (float*)(L + CBP_OFF + 32768);                 // 16384 B
    const float* Wu1b = Wu1 + HH * HH;
    for (int i = tid; i < HH * HH / 2; i += 1024) {
      const float2 w = ((const float2*)Wu1b)[i];
      ((unsigned*)WuLh)[i] = f2h2(w.x, w.y);
    }
    if (tid < 32 * HH / 4)
      ((float4*)WmL)[tid] = ((const float4*)(Wm2 + bs * 32 * HH))[tid];
    __syncthreads();
    const int kk = tid >> 5;
    const int k  = bs * 32 + kk;
    const int cg = tid & 31;
    f32x4 acc = (f32x4)0.f;
    for (int j = 0; j < HH; ++j) {
      const float a = WmL[kk * HH + j];
      const uint2 u = *(const uint2*)(WuLh + j * HH + cg * 4);
      acc[0] += a * h2f((unsigned short)(u.x & 0xffff));
      acc[1] += a * h2f((unsigned short)(u.x >> 16));
      acc[2] += a * h2f((unsigned short)(u.y & 0xffff));
      acc[3] += a * h2f((unsigned short)(u.y >> 16));
    }
    unsigned short* dst = (unsigned short*)ws;
#pragma unroll
    for (int q = 0; q < 4; ++q) {
      const int c = cg * 4 + q;
      const int nt = c >> 4;
      const int l = (((k & 31) >> 3) << 4) | (c & 15);
      dst[(size_t)2 * 16384 + (((nt * 4 + bs) * 64) + l) * 8 + (k & 7)] = f2h(acc[q]);
    }
    if (bs == 0 && tid < HH) {
      float s = 0.f;
      for (int j = 0; j < HH; ++j) s += bm2[j] * h2f(WuLh[j * HH + tid]);
      ((float*)(ws + BC_OFF))[tid] = s;
    }
  }

  __threadfence();
  cooperative_groups::this_grid().sync();

  // ---- post-sync: B-frag preload + csr/offs/bias staging ----
  const unsigned short* wpk = (const unsigned short*)ws;
  const int nt0 = wave & 7;
  const int mt0 = 3 * (wave >> 3);
  const int erow = (lane >> 4) * 4;
  const int ecol = lane & 15;
  const int C    = nt0 * 16 + ecol;

  f16x8 BA0[4], BA1[4];
  loadB(wpk, nt0, lane, BA0);
  loadB(wpk + 16384, nt0, lane, BA1);
  {
    const int* wofs = (const int*)(ws + OFFS_OFF);
    const int* wcsr = (const int*)(ws + CSR_OFF);
    const float* wbc = (const float*)(ws + BC_OFF);
    for (int i = tid; i < EE; i += 1024) csrL[i] = wcsr[i];
    if (tid < NN + 1) offsL[tid] = wofs[tid];
    if (tid < HH) {
      bias[0][tid] = bm1[tid];  bias[1][tid] = wbc[tid];
      bias[2][tid] = bu1[tid];  bias[3][tid] = bu2[tid];
      bias[4][tid] = gamma_[tid]; bias[5][tid] = beta_[tid];
    }
  }
  __syncthreads();

  // ---- GEMM A: P = Xb@Wm1t -> bufP ; Q' = Xb@Wm1b + bm1 -> bufQ ----
  {
    f32x4 accP[3], accQ[3];
#pragma unroll
    for (int mm = 0; mm < 3; ++mm) { accP[mm] = (f32x4)0.f; accQ[mm] = (f32x4)0.f; }
    gemm3x2(Xb, BA0, BA1, lane, mt0, accP, accQ);
#pragma unroll
    for (int mm = 0; mm < 3; ++mm)
#pragma unroll
      for (int rg = 0; rg < 4; ++rg) {
        const int R = (mt0 + mm) * 16 + erow + rg;
        const unsigned byte = swzu(R, C * 2);
        const bool ok = (R < NN);
        *(unsigned short*)(bufP + byte) = ok ? f2h(accP[mm][rg]) : (unsigned short)0;
        *(unsigned short*)(bufQ + byte) = ok ? f2h(accQ[mm][rg] + bias[0][C]) : (unsigned short)0;
      }
  }
  __syncthreads();

  // ---- edge aggregation, packed fp16 (x4 unrolled) ----
  {
    const int lb = lane * 4;
    for (int t = wave; t < NN; t += 16) {
      const unsigned qbyte = swzu(t, lb);
      const unsigned q = *(const unsigned*)(bufQ + qbyte);
      unsigned h = 0u, g = 0u;
      int e = offsL[t];
      const int o1 = offsL[t + 1];
      for (; e + 4 <= o1; e += 4) {
        const int s0 = csrL[e], s1 = csrL[e + 1], s2 = csrL[e + 2], s3 = csrL[e + 3];
        const unsigned p0 = *(const unsigned*)(bufP + swzu(s0, lb));
        const unsigned p1 = *(const unsigned*)(bufP + swzu(s1, lb));
        const unsigned p2 = *(const unsigned*)(bufP + swzu(s2, lb));
        const unsigned p3 = *(const unsigned*)(bufP + swzu(s3, lb));
        h = pk_add(h, pk_relu(pk_add(p0, q)));
        g = pk_add(g, pk_relu(pk_add(p1, q)));
        h = pk_add(h, pk_relu(pk_add(p2, q)));
        g = pk_add(g, pk_relu(pk_add(p3, q)));
      }
      for (; e < o1; ++e) {
        const int s = csrL[e];
        const unsigned pp = *(const unsigned*)(bufP + swzu(s, lb));
        h = pk_add(h, pk_relu(pk_add(pp, q)));
      }
      h = pk_add(h, g);
      *(unsigned*)(bufQ + qbyte) = h;
    }
  }
  __syncthreads();

  // ---- GEMM BC: T = Hsum@Wc ; U = Xb@Wu1t ; h2 -> bufP ----
  {
    f16x8 BW[4], BU[4];
    loadB(wpk + 2 * 16384, nt0, lane, BW);
    loadB(wpk + 3 * 16384, nt0, lane, BU);
    f32x4 accT[3], accU[3];
#pragma unroll
    for (int mm = 0; mm < 3; ++mm) { accT[mm] = (f32x4)0.f; accU[mm] = (f32x4)0.f; }
    gemm3_2A(bufQ, Xb, BW, BU, lane, mt0, accT, accU);
#pragma unroll
    for (int mm = 0; mm < 3; ++mm)
#pragma unroll
      for (int rg = 0; rg < 4; ++rg) {
        const int R = (mt0 + mm) * 16 + erow + rg;
        float v = 0.f;
        if (R < NN) {
          const int dg = offsL[R + 1] - offsL[R];
          const float inv = (dg > 0) ? 1.f / (float)dg : 1.f;
          const float sf  = (dg > 0) ? 1.f : 0.f;
          v = fmaxf(accU[mm][rg] + accT[mm][rg] * inv + sf * bias[1][C] + bias[2][C], 0.f);
        }
        *(unsigned short*)(bufP + swzu(R, C * 2)) = f2h(v);
      }
  }
  __syncthreads();

  // ---- GEMM D: x = X + h2@Wu2 + bu2 (in place into X fp32) ----
  {
    f16x8 BD[4];
    loadB(wpk + 5 * 16384, nt0, lane, BD);
    f32x4 acc[3];
#pragma unroll
    for (int mm = 0; mm < 3; ++mm) acc[mm] = (f32x4)0.f;
    gemm3(bufP, BD, lane, mt0, acc);
#pragma unroll
    for (int mm = 0; mm < 3; ++mm)
#pragma unroll
      for (int rg = 0; rg < 4; ++rg) {
        const int R = (mt0 + mm) * 16 + erow + rg;
        if (R < NN) X[R][C] += acc[mm][rg] + bias[3][C];
      }
  }
  __syncthreads();

  // ---- LayerNorm per row + store ----
  for (int r = wave; r < NN; r += 16) {
    const float x0 = X[r][lane], x1 = X[r][lane + 64];
    float s = x0 + x1;
#pragma unroll
    for (int off = 32; off; off >>= 1) s += __shfl_xor(s, off);
    const float mu = s * (1.f / 128.f);
    const float d0 = x0 - mu, d1 = x1 - mu;
    float v = d0 * d0 + d1 * d1;
#pragma unroll
    for (int off = 32; off; off >>= 1) v += __shfl_xor(v, off);
    const float rstd = rsqrtf(v * (1.f / 128.f) + 1e-5f);
    const size_t o = ((size_t)b * NN + r) * HH;
    out[o + lane]      = d0 * rstd * bias[4][lane]      + bias[5][lane];
    out[o + lane + 64] = d1 * rstd * bias[4][lane + 64] + bias[5][lane + 64];
  }
}

// =================== fallback: r11 two-kernel fp16 path ======================
__global__ __launch_bounds__(1024)
void setup_kernel(const float* __restrict__ Wm1, const float* __restrict__ Wm2,
                  const float* __restrict__ Wu1, const float* __restrict__ Wu2,
                  const float* __restrict__ bm2, const int* __restrict__ eidx,
                  char* __restrict__ ws) {
  __shared__ __align__(16) char arena[81920];
  const int tid = threadIdx.x;

  if (blockIdx.x < 8) {
    const int gid = blockIdx.x * 1024 + tid;
    const int lane = gid & 63;
    const int t = gid >> 6;
    const int ks = t & 3, nt = (t >> 2) & 7, mat = t >> 5;
    const float* src;
    int slot;
    if (mat == 0)      { src = Wm1;           slot = 0; }
    else if (mat == 1) { src = Wm1 + HH * HH; slot = 1; }
    else if (mat == 2) { src = Wu1;           slot = 3; }
    else               { src = Wu2;           slot = 5; }
    const int c = nt * 16 + (lane & 15);
    const int k0 = ks * 32 + (lane >> 4) * 8;
    f16x8 pv;
#pragma unroll
    for (int j = 0; j < 8; ++j) pv[j] = (_Float16)src[(k0 + j) * HH + c];
    *(f16x8*)((unsigned short*)ws + (size_t)slot * 16384 + (((nt * 4 + ks) * 64) + lane) * 8) = pv;
    return;
  }

  if (blockIdx.x == 8) {
    int* srcE  = (int*)arena;
    int* tgtE  = srcE + EE;
    int* rankS = tgtE + EE;
    int* cntC  = rankS + EE;
    int* tot   = cntC + NCHK * NN;
    int* scanS = tot + NN;
    int* wsumS = scanS + 128;
    int* offsS = wsumS + 2;
    for (int i = tid; i < NCHK * NN; i += 1024) cntC[i] = 0;
    for (int i = tid; i < 2 * EE; i += 1024) srcE[i] = eidx[i];
    __syncthreads();
    const int lane = tid & 63, wv = tid >> 6;
    for (int c = wv; c < NCHK; c += 16) {
      const int e = c * 64 + lane;
      const bool ok = (e < EE);
      const int t = ok ? tgtE[e] : -1;
      unsigned long long mymask = 0;
#pragma unroll
      for (int i = 0; i < 64; ++i) {
        const int ti = __shfl(t, i);
        const unsigned long long bal = __ballot(t == ti);
        if (i == lane) mymask = bal;
      }
      if (ok) {
        const int rank = __popcll(mymask & ((1ull << lane) - 1ull));
        rankS[e] = rank;
        if (rank == 0) cntC[c * NN + t] = __popcll(mymask);
      }
    }
    __syncthreads();
    if (tid < NN) {
      int s = 0;
#pragma unroll
      for (int c = 0; c < NCHK; ++c) s += cntC[c * NN + tid];
      tot[tid] = s;
    }
    __syncthreads();
    if (tid < 128) {
      const int l = tid & 63, w = tid >> 6;
      int inc = (tid < NN) ? tot[tid] : 0;
#pragma unroll
      for (int d = 1; d < 64; d <<= 1) {
        int u = __shfl_up(inc, d);
        if (l >= d) inc += u;
      }
      scanS[tid] = inc;
      if (l == 63) wsumS[w] = inc;
    }
    __syncthreads();
    if (tid < 128) {
      const int w = tid >> 6;
      const int inc = scanS[tid] + (w ? wsumS[0] : 0);
      if (tid < NN) offsS[tid] = inc - tot[tid];
      if (tid == NN - 1) offsS[NN] = inc;
    }
    __syncthreads();
    if (tid < NN) {
      int run = offsS[tid];
#pragma unroll
      for (int c = 0; c < NCHK; ++c) {
        const int tmp = cntC[c * NN + tid];
        cntC[c * NN + tid] = run;
        run += tmp;
      }
    }
    __syncthreads();
    int* wofs = (int*)(ws + OFFS_OFF);
    int* wcsr = (int*)(ws + CSR_OFF);
    for (int i = tid; i <= NN; i += 1024) wofs[i] = offsS[i];
    for (int e = tid; e < EE; e += 1024) {
      const int t = tgtE[e];
      wcsr[cntC[(e >> 6) * NN + t] + rankS[e]] = srcE[e];
    }
    return;
  }

  {
    const int bs = blockIdx.x - 9;
    float* WuL = (float*)arena;
    float* WmL = WuL + HH * HH;
    const float* Wu1b = Wu1 + HH * HH;
    float4* WuL4 = (float4*)WuL;
    const float4* src4 = (const float4*)Wu1b;
    for (int i = tid; i < HH * HH / 4; i += 1024) WuL4[i] = src4[i];
    const float4* wm4 = (const float4*)(Wm2 + bs * 32 * HH);
    float4* WmL4 = (float4*)WmL;
    if (tid < 32 * HH / 4) WmL4[tid] = wm4[tid];
    __syncthreads();
    const int kk = tid >> 5;
    const int k  = bs * 32 + kk;
    const int cg = tid & 31;
    f32x4 acc = (f32x4)0.f;
    for (int j = 0; j < HH; ++j) {
      const float a = WmL[kk * HH + j];
      const float4 w = WuL4[j * 32 + cg];
      acc[0] += a * w.x; acc[1] += a * w.y; acc[2] += a * w.z; acc[3] += a * w.w;
    }
    unsigned short* dst = (unsigned short*)ws;
#pragma unroll
    for (int q = 0; q < 4; ++q) {
      const int c = cg * 4 + q;
      const int nt = c >> 4;
      const int l = (((k & 31) >> 3) << 4) | (c & 15);
      dst[(size_t)2 * 16384 + (((nt * 4 + bs) * 64) + l) * 8 + (k & 7)] = f2h(acc[q]);
    }
    if (bs == 0 && tid < HH) {
      float s = 0.f;
      for (int j = 0; j < HH; ++j) s += bm2[j] * WuL[j * HH + tid];
      ((float*)(ws + BC_OFF))[tid] = s;
    }
  }
}

__global__ __launch_bounds__(1024, 4)
void mpnn_fp16_kernel(const float* __restrict__ node,
                      const float* __restrict__ bm1,
                      const float* __restrict__ bu1, const float* __restrict__ bu2,
                      const float* __restrict__ gamma_, const float* __restrict__ beta_,
                      const char* __restrict__ ws,
                      float* __restrict__ out) {
  __shared__ float X[NN][HH];
  __shared__ unsigned short XbS[MPAD * HH];
  __shared__ unsigned short bufPS[MPAD * HH];
  __shared__ unsigned short bufQS[MPAD * HH];
  __shared__ int   csrL[EE];
  __shared__ int   offsL[NN + 1];
  __shared__ float bias[6][HH];
  char* Xb   = (char*)XbS;
  char* bufP = (char*)bufPS;
  char* bufQ = (char*)bufQS;

  const int tid  = threadIdx.x;
  const int lane = tid & 63;
  const int wave = tid >> 6;
  const int b    = blockIdx.x;

  const unsigned short* wpk = (const unsigned short*)ws;
  const int* wofs = (const int*)(ws + OFFS_OFF);
  const int* wcsr = (const int*)(ws + CSR_OFF);
  const float* wbc = (const float*)(ws + BC_OFF);

  const int nt0 = wave & 7;
  const int mt0 = 3 * (wave >> 3);
  const int erow = (lane >> 4) * 4;
  const int ecol = lane & 15;
  const int C    = nt0 * 16 + ecol;

  f16x8 BA0[4], BA1[4];
  loadB(wpk, nt0, lane, BA0);
  loadB(wpk + 16384, nt0, lane, BA1);

  {
    const float4* nf4 = (const float4*)(node + (size_t)b * NN * HH);
    const int i2 = tid + 2048;
    const bool has2 = (i2 < NN * HH / 4);
    float4 v0 = nf4[tid];
    float4 v1 = nf4[tid + 1024];
    float4 v2 = has2 ? nf4[i2] : make_float4(0.f, 0.f, 0.f, 0.f);
#pragma unroll
    for (int k = 0; k < 3; ++k) {
      const int i = tid + k * 1024;
      if (k == 2 && !has2) break;
      const float4 v = (k == 0) ? v0 : (k == 1) ? v1 : v2;
      const int r = i >> 5, c = (i & 31) * 4;
      *(float4*)&X[r][c] = v;
      uint2 pv; pv.x = f2h2(v.x, v.y); pv.y = f2h2(v.z, v.w);
      *(uint2*)(Xb + swzu(r, c * 2)) = pv;
    }
    if (tid < (MPAD - NN) * 16) {
      const int r = NN + tid / 16, m = tid % 16;
      ushort8v z = {0,0,0,0,0,0,0,0};
      *(ushort8v*)(Xb + swzu(r, m * 16)) = z;
    }
    for (int i = tid; i < EE; i += 1024) csrL[i] = wcsr[i];
    if (tid < NN + 1) offsL[tid] = wofs[tid];
    if (tid < HH) {
      bias[0][tid] = bm1[tid];  bias[1][tid] = wbc[tid];
      bias[2][tid] = bu1[tid];  bias[3][tid] = bu2[tid];
      bias[4][tid] = gamma_[tid]; bias[5][tid] = beta_[tid];
    }
  }
  __syncthreads();

  {
    f32x4 accP[3], accQ[3];
#pragma unroll
    for (int mm = 0; mm < 3; ++mm) { accP[mm] = (f32x4)0.f; accQ[mm] = (f32x4)0.f; }
    gemm3x2(Xb, BA0, BA1, lane, mt0, accP, accQ);
#pragma unroll
    for (int mm = 0; mm < 3; ++mm)
#pragma unroll
      for (int rg = 0; rg < 4; ++rg) {
        const int R = (mt0 + mm) * 16 + erow + rg;
        const unsigned byte = swzu(R, C * 2);
        const bool ok = (R < NN);
        *(unsigned short*)(bufP + byte) = ok ? f2h(accP[mm][rg]) : (unsigned short)0;
        *(unsigned short*)(bufQ + byte) = ok ? f2h(accQ[mm][rg] + bias[0][C]) : (unsigned short)0;
      }
  }
  __syncthreads();

  {
    const int lb = lane * 4;
    for (int t = wave; t < NN; t += 16) {
      const unsigned qbyte = swzu(t, lb);
      const unsigned q = *(const unsigned*)(bufQ + qbyte);
      unsigned h = 0u, g = 0u;
      int e = offsL[t];
      const int o1 = offsL[t + 1];
      for (; e + 4 <= o1; e += 4) {
        const int s0 = csrL[e], s1 = csrL[e + 1], s2 = csrL[e + 2], s3 = csrL[e + 3];
        const unsigned p0 = *(const unsigned*)(bufP + swzu(s0, lb));
        const unsigned p1 = *(const unsigned*)(bufP + swzu(s1, lb));
        const unsigned p2 = *(const unsigned*)(bufP + swzu(s2, lb));
        const unsigned p3 = *(const unsigned*)(bufP + swzu(s3, lb));
        h = pk_add(h, pk_relu(pk_add(p0, q)));
        g = pk_add(g, pk_relu(pk_add(p1, q)));
        h = pk_add(h, pk_relu(pk_add(p2, q)));
        g = pk_add(g, pk_relu(pk_add(p3, q)));
      }
      for (; e < o1; ++e) {
        const int s = csrL[e];
        const unsigned pp = *(const unsigned*)(bufP + swzu(s, lb));
        h = pk_add(h, pk_relu(pk_add(pp, q)));
      }
      h = pk_add(h, g);
      *(unsigned*)(bufQ + qbyte) = h;
    }
  }
  __syncthreads();

  {
    f16x8 BW[4], BU[4];
    loadB(wpk + 2 * 16384, nt0, lane, BW);
    loadB(wpk + 3 * 16384, nt0, lane, BU);
    f32x4 accT[3], accU[3];
#pragma unroll
    for (int mm = 0; mm < 3; ++mm) { accT[mm] = (f32x4)0.f; accU[mm] = (f32x4)0.f; }
    gemm3_2A(bufQ, Xb, BW, BU, lane, mt0, accT, accU);
#pragma unroll
    for (int mm = 0; mm < 3; ++mm)
#pragma unroll
      for (int rg = 0; rg < 4; ++rg) {
        const int R = (mt0 + mm) * 16 + erow + rg;
        float v = 0.f;
        if (R < NN) {
          const int dg = offsL[R + 1] - offsL[R];
          const float inv = (dg > 0) ? 1.f / (float)dg : 1.f;
          const float sf  = (dg > 0) ? 1.f : 0.f;
          v = fmaxf(accU[mm][rg] + accT[mm][rg] * inv + sf * bias[1][C] + bias[2][C], 0.f);
        }
        *(unsigned short*)(bufP + swzu(R, C * 2)) = f2h(v);
      }
  }
  __syncthreads();

  {
    f16x8 BD[4];
    loadB(wpk + 5 * 16384, nt0, lane, BD);
    f32x4 acc[3];
#pragma unroll
    for (int mm = 0; mm < 3; ++mm) acc[mm] = (f32x4)0.f;
    gemm3(bufP, BD, lane, mt0, acc);
#pragma unroll
    for (int mm = 0; mm < 3; ++mm)
#pragma unroll
      for (int rg = 0; rg < 4; ++rg) {
        const int R = (mt0 + mm) * 16 + erow + rg;
        if (R < NN) X[R][C] += acc[mm][rg] + bias[3][C];
      }
  }
  __syncthreads();

  for (int r = wave; r < NN; r += 16) {
    const float x0 = X[r][lane], x1 = X[r][lane + 64];
    float s = x0 + x1;
#pragma unroll
    for (int off = 32; off; off >>= 1) s += __shfl_xor(s, off);
    const float mu = s * (1.f / 128.f);
    const float d0 = x0 - mu, d1 = x1 - mu;
    float v = d0 * d0 + d1 * d1;
#pragma unroll
    for (int off = 32; off; off >>= 1) v += __shfl_xor(v, off);
    const float rstd = rsqrtf(v * (1.f / 128.f) + 1e-5f);
    const size_t o = ((size_t)b * NN + r) * HH;
    out[o + lane]      = d0 * rstd * bias[4][lane]      + bias[5][lane];
    out[o + lane + 64] = d1 * rstd * bias[4][lane + 64] + bias[5][lane + 64];
  }
}

extern "C" void kernel_launch(void* const* d_in, const int* in_sizes, int n_in,
                              void* d_out, int out_size, void* d_ws, size_t ws_size,
                              hipStream_t stream) {
  (void)in_sizes; (void)n_in; (void)out_size;
  const float* node  = (const float*)d_in[0];
  const int*   eidx  = (const int*)  d_in[1];
  const float* Wm1   = (const float*)d_in[2];
  const float* bm1   = (const float*)d_in[3];
  const float* Wm2   = (const float*)d_in[4];
  const float* bm2   = (const float*)d_in[5];
  const float* Wu1   = (const float*)d_in[6];
  const float* bu1   = (const float*)d_in[7];
  const float* Wu2   = (const float*)d_in[8];
  const float* bu2   = (const float*)d_in[9];
  const float* gamma_= (const float*)d_in[10];
  const float* beta_ = (const float*)d_in[11];
  float* outp = (float*)d_out;
  char* ws = (char*)d_ws;

  if (ws_size >= (size_t)WS_NEED) {
    void* kargs[] = {(void*)&node, (void*)&eidx, (void*)&Wm1, (void*)&bm1,
                     (void*)&Wm2, (void*)&bm2, (void*)&Wu1, (void*)&bu1,
                     (void*)&Wu2, (void*)&bu2, (void*)&gamma_, (void*)&beta_,
                     (void*)&ws, (void*)&outp};
    hipError_t err = hipLaunchCooperativeKernel((const void*)mpnn_coop_kernel,
                                                dim3(256), dim3(1024), kargs, 0, stream);
    if (err != hipSuccess) {
      hipLaunchKernelGGL(setup_kernel, dim3(13), dim3(1024), 0, stream,
                         Wm1, Wm2, Wu1, Wu2, bm2, eidx, ws);
      hipLaunchKernelGGL(mpnn_fp16_kernel, dim3(256), dim3(1024), 0, stream,
                         node, bm1, bu1, bu2, gamma_, beta_, ws, outp);
    }
  } else {
    // ws too small: two-kernel path still needs ws; as a last resort run it
    // anyway on whatever ws exists (never happens in this harness: ws >> 200KB)
    hipLaunchKernelGGL(setup_kernel, dim3(13), dim3(1024), 0, stream,
                       Wm1, Wm2, Wu1, Wu2, bm2, eidx, ws);
    hipLaunchKernelGGL(mpnn_fp16_kernel, dim3(256), dim3(1024), 0, stream,
                       node, bm1, bu1, bu2, gamma_, beta_, ws, outp);
  }
}

// Round 13
// 115.212 us; speedup vs baseline: 1.3021x; 1.3021x over previous
//
#include <hip/hip_runtime.h>

// Fused MPNN layer, B=256, N=81, H=128, E=1620 — single kernel, flag-sync.
//   P = X @ Wm1[:H],  Q' = X @ Wm1[H:] + bm1
//   Hsum[t] = sum_{e: tgt=t} relu(P[src_e] + Q'[t])
//   Folded:  agg@Wu1b = (Hsum@Wc)*inv_deg + 1[deg>0]*bc,  Wc=Wm2@Wu1b, bc=bm2@Wu1b
//   h2 = relu(X@Wu1t + (Hsum@Wc)*inv + s*bc + bu1)
//   x  = X + h2 @ Wu2 + bu2 ;  out = LayerNorm(x)*gamma + beta
// ONE kernel, grid 256 x 1024 (1 block/CU). Blocks 0-12 run setup (weight pack
// to fp16 frag order / ballot-CSR / Wc+bc) then release a device-scope flag in
// ws; every block stages its own X meanwhile, acquire-polls flag==13, and runs
// the fp16 MFMA pipeline (identical to r11). Flag zeroed per call by
// hipMemsetAsync (graph-safe). Fallback: r11 two-kernel path if ws too small.

#define NN 81
#define HH 128
#define EE 1620
#define NCHK 26                         // ceil(EE/64)
#define MPAD 96
#define WB_BYTES 196608                 // 6 * 16384 ushorts (slot4 unused)
#define OFFS_OFF (WB_BYTES)             // int offs[82]
#define CSR_OFF  (OFFS_OFF + 82 * 4)    // int csr[1620]
#define BC_OFF   (CSR_OFF + EE * 4)     // float bc[128]
#define FLAG_OFF (BC_OFF + HH * 4)      // int flag
#define WS_NEED  (FLAG_OFF + 4)

// kernel LDS arena (bytes)
#define CX_OFF    0                     // float X[81][128]      41472
#define CXB_OFF   41472                 // fp16 swz [96][128]    24576
#define CBP_OFF   66048                 // fp16 swz [96][128]    24576
#define CBQ_OFF   90624                 // fp16 swz [96][128]    24576
#define CCSR_OFF  115200                // int[1620]              6480
#define COFF_OFF  121680                // int[82]                 328
#define CBIAS_OFF 122008                // float[6][128]          3072
#define CL_BYTES  125080

typedef _Float16 f16x8 __attribute__((ext_vector_type(8)));
typedef __fp16   h16x2 __attribute__((ext_vector_type(2)));
typedef __attribute__((ext_vector_type(8))) unsigned short ushort8v;
typedef __attribute__((ext_vector_type(4))) float f32x4;

__device__ __forceinline__ unsigned short f2h(float f) {
  union { _Float16 h; unsigned short u; } v; v.h = (_Float16)f; return v.u;
}
__device__ __forceinline__ float h2f(unsigned short u) {
  union { unsigned short u; _Float16 h; } v; v.u = u; return (float)v.h;
}
__device__ __forceinline__ unsigned f2h2(float x, float y) {   // v_cvt_pkrtz
  union { h16x2 h; unsigned u; } v;
  v.h = __builtin_amdgcn_cvt_pkrtz(x, y);
  return v.u;
}
__device__ __forceinline__ unsigned pk_add(unsigned a, unsigned b) {
  unsigned r; asm("v_pk_add_f16 %0, %1, %2" : "=v"(r) : "v"(a), "v"(b)); return r;
}
__device__ __forceinline__ unsigned pk_relu(unsigned a) {
  unsigned r; asm("v_pk_max_f16 %0, %1, %2" : "=v"(r) : "v"(a), "v"(0u)); return r;
}
__device__ __forceinline__ unsigned swzu(int r, int laneb) {
  return ((unsigned)(r * 256 + laneb)) ^ ((unsigned)((r & 7) << 4));
}

// ---------------- MFMA helpers (fp16, per wave: 3 M-tiles x 1 N-tile) --------
__device__ __forceinline__ void loadB(const unsigned short* Wp, int nt0, int lane,
                                      f16x8 (&Bf)[4]) {
#pragma unroll
  for (int ks = 0; ks < 4; ++ks)
    Bf[ks] = *(const f16x8*)(Wp + ((nt0 * 4 + ks) * 64 + lane) * 8);
}

__device__ __forceinline__ void gemm3(const char* Ab, const f16x8 (&Bf)[4],
                                      int lane, int mt0, f32x4 (&acc)[3]) {
  const int rl = lane & 15;
  const int kb = (lane >> 4) * 16;
  const unsigned swz = (unsigned)((rl & 7) << 4);
#pragma unroll
  for (int ks = 0; ks < 4; ++ks)
#pragma unroll
    for (int mm = 0; mm < 3; ++mm) {
      const int r = (mt0 + mm) * 16 + rl;
      const unsigned byte = (unsigned)(r * 256) + (((unsigned)(ks * 64 + kb)) ^ swz);
      f16x8 a = *(const f16x8*)(Ab + byte);
      acc[mm] = __builtin_amdgcn_mfma_f32_16x16x32_f16(a, Bf[ks], acc[mm], 0, 0, 0);
    }
}

__device__ __forceinline__ void gemm3x2(const char* Ab,
                                        const f16x8 (&B0)[4], const f16x8 (&B1)[4],
                                        int lane, int mt0,
                                        f32x4 (&a0)[3], f32x4 (&a1)[3]) {
  const int rl = lane & 15;
  const int kb = (lane >> 4) * 16;
  const unsigned swz = (unsigned)((rl & 7) << 4);
#pragma unroll
  for (int ks = 0; ks < 4; ++ks)
#pragma unroll
    for (int mm = 0; mm < 3; ++mm) {
      const int r = (mt0 + mm) * 16 + rl;
      const unsigned byte = (unsigned)(r * 256) + (((unsigned)(ks * 64 + kb)) ^ swz);
      f16x8 a = *(const f16x8*)(Ab + byte);
      a0[mm] = __builtin_amdgcn_mfma_f32_16x16x32_f16(a, B0[ks], a0[mm], 0, 0, 0);
      a1[mm] = __builtin_amdgcn_mfma_f32_16x16x32_f16(a, B1[ks], a1[mm], 0, 0, 0);
    }
}

__device__ __forceinline__ void gemm3_2A(const char* A0, const char* A1,
                                         const f16x8 (&B0)[4], const f16x8 (&B1)[4],
                                         int lane, int mt0,
                                         f32x4 (&a0)[3], f32x4 (&a1)[3]) {
  const int rl = lane & 15;
  const int kb = (lane >> 4) * 16;
  const unsigned swz = (unsigned)((rl & 7) << 4);
#pragma unroll
  for (int ks = 0; ks < 4; ++ks)
#pragma unroll
    for (int mm = 0; mm < 3; ++mm) {
      const int r = (mt0 + mm) * 16 + rl;
      const unsigned byte = (unsigned)(r * 256) + (((unsigned)(ks * 64 + kb)) ^ swz);
      f16x8 x0 = *(const f16x8*)(A0 + byte);
      a0[mm] = __builtin_amdgcn_mfma_f32_16x16x32_f16(x0, B0[ks], a0[mm], 0, 0, 0);
      f16x8 x1 = *(const f16x8*)(A1 + byte);
      a1[mm] = __builtin_amdgcn_mfma_f32_16x16x32_f16(x1, B1[ks], a1[mm], 0, 0, 0);
    }
}

// =================== single kernel with flag sync ============================
__global__ __launch_bounds__(1024, 4)
void mpnn_flag_kernel(const float* __restrict__ node, const int* __restrict__ eidx,
                      const float* __restrict__ Wm1, const float* __restrict__ bm1,
                      const float* __restrict__ Wm2, const float* __restrict__ bm2,
                      const float* __restrict__ Wu1, const float* __restrict__ bu1,
                      const float* __restrict__ Wu2, const float* __restrict__ bu2,
                      const float* __restrict__ gamma_, const float* __restrict__ beta_,
                      char* __restrict__ ws, float* __restrict__ out) {
  __shared__ __align__(16) char L[CL_BYTES];
  float (*X)[HH] = (float(*)[HH])(L + CX_OFF);
  char* Xb   = L + CXB_OFF;
  char* bufP = L + CBP_OFF;
  char* bufQ = L + CBQ_OFF;
  int*  csrL = (int*)(L + CCSR_OFF);
  int*  offsL= (int*)(L + COFF_OFF);
  float (*bias)[HH] = (float(*)[HH])(L + CBIAS_OFF);
  int* flag = (int*)(ws + FLAG_OFF);

  const int tid  = threadIdx.x;
  const int lane = tid & 63;
  const int wave = tid >> 6;     // 0..15
  const int b    = blockIdx.x;

  // ================= setup roles (blocks 0-12) FIRST =================
  if (b < 8) {
    // pack {Wm1t,Wm1b,Wu1t,Wu2} -> fp16 frag order in ws
    const int gid = b * 1024 + tid;
    const int ln = gid & 63;
    const int t = gid >> 6;                 // 0..127
    const int ks = t & 3, nt = (t >> 2) & 7, mat = t >> 5;
    const float* src;
    int slot;
    if (mat == 0)      { src = Wm1;           slot = 0; }
    else if (mat == 1) { src = Wm1 + HH * HH; slot = 1; }
    else if (mat == 2) { src = Wu1;           slot = 3; }
    else               { src = Wu2;           slot = 5; }
    const int c = nt * 16 + (ln & 15);
    const int k0 = ks * 32 + (ln >> 4) * 8;
    f16x8 pv;
#pragma unroll
    for (int j = 0; j < 8; ++j) pv[j] = (_Float16)src[(k0 + j) * HH + c];
    *(f16x8*)((unsigned short*)ws + (size_t)slot * 16384 + (((nt * 4 + ks) * 64) + ln) * 8) = pv;
  } else if (b == 8) {
    // deterministic CSR via ballot match-masks; scratch overlays bufP/bufQ
    int* srcE  = (int*)(L + CBP_OFF);    // EE
    int* tgtE  = srcE + EE;              // EE
    int* rankS = tgtE + EE;              // EE
    int* cntC  = rankS + EE;             // NCHK*NN
    int* tot   = cntC + NCHK * NN;       // NN
    int* scanS = tot + NN;               // 128
    int* wsumS = scanS + 128;            // 2
    int* offsS = wsumS + 2;              // NN+1
    for (int i = tid; i < NCHK * NN; i += 1024) cntC[i] = 0;
    for (int i = tid; i < 2 * EE; i += 1024) srcE[i] = eidx[i];
    __syncthreads();
    const int ln = tid & 63, wv = tid >> 6;
    for (int c = wv; c < NCHK; c += 16) {
      const int e = c * 64 + ln;
      const bool ok = (e < EE);
      const int t = ok ? tgtE[e] : -1;
      unsigned long long mymask = 0;
#pragma unroll
      for (int i = 0; i < 64; ++i) {
        const int ti = __shfl(t, i);
        const unsigned long long bal = __ballot(t == ti);
        if (i == ln) mymask = bal;
      }
      if (ok) {
        const int rank = __popcll(mymask & ((1ull << ln) - 1ull));
        rankS[e] = rank;
        if (rank == 0) cntC[c * NN + t] = __popcll(mymask);
      }
    }
    __syncthreads();
    if (tid < NN) {
      int s = 0;
#pragma unroll
      for (int c = 0; c < NCHK; ++c) s += cntC[c * NN + tid];
      tot[tid] = s;
    }
    __syncthreads();
    if (tid < 128) {
      const int l = tid & 63, w = tid >> 6;
      int inc = (tid < NN) ? tot[tid] : 0;
#pragma unroll
      for (int d = 1; d < 64; d <<= 1) {
        int u = __shfl_up(inc, d);
        if (l >= d) inc += u;
      }
      scanS[tid] = inc;
      if (l == 63) wsumS[w] = inc;
    }
    __syncthreads();
    if (tid < 128) {
      const int w = tid >> 6;
      const int inc = scanS[tid] + (w ? wsumS[0] : 0);
      if (tid < NN) offsS[tid] = inc - tot[tid];
      if (tid == NN - 1) offsS[NN] = inc;
    }
    __syncthreads();
    if (tid < NN) {
      int run = offsS[tid];
#pragma unroll
      for (int c = 0; c < NCHK; ++c) {
        const int tmp = cntC[c * NN + tid];
        cntC[c * NN + tid] = run;
        run += tmp;
      }
    }
    __syncthreads();
    int* wofs = (int*)(ws + OFFS_OFF);
    int* wcsr = (int*)(ws + CSR_OFF);
    for (int i = tid; i <= NN; i += 1024) wofs[i] = offsS[i];
    for (int e = tid; e < EE; e += 1024) {
      const int t = tgtE[e];
      wcsr[cntC[(e >> 6) * NN + t] + rankS[e]] = srcE[e];
    }
    __syncthreads();                     // scratch dead before staging reuse
  } else if (b < 13) {
    // Wc = Wm2 @ Wu1b rows [32*bs,32*bs+32); fp16 WuL scratch overlays bufP/bufQ
    const int bs = b - 9;
    unsigned short* WuLh = (unsigned short*)(L + CBP_OFF);      // 32768 B
    float* WmL = (float*)(L + CBP_OFF + 32768);                 // 16384 B
    const float* Wu1b = Wu1 + HH * HH;
    for (int i = tid; i < HH * HH / 2; i += 1024) {
      const float2 w = ((const float2*)Wu1b)[i];
      ((unsigned*)WuLh)[i] = f2h2(w.x, w.y);
    }
    if (tid < 32 * HH / 4)
      ((float4*)WmL)[tid] = ((const float4*)(Wm2 + bs * 32 * HH))[tid];
    __syncthreads();
    const int kk = tid >> 5;
    const int k  = bs * 32 + kk;
    const int cg = tid & 31;
    f32x4 acc = (f32x4)0.f;
    for (int j = 0; j < HH; ++j) {
      const float a = WmL[kk * HH + j];
      const uint2 u = *(const uint2*)(WuLh + j * HH + cg * 4);
      acc[0] += a * h2f((unsigned short)(u.x & 0xffff));
      acc[1] += a * h2f((unsigned short)(u.x >> 16));
      acc[2] += a * h2f((unsigned short)(u.y & 0xffff));
      acc[3] += a * h2f((unsigned short)(u.y >> 16));
    }
    unsigned short* dst = (unsigned short*)ws;
#pragma unroll
    for (int q = 0; q < 4; ++q) {
      const int c = cg * 4 + q;
      const int nt = c >> 4;
      const int l = (((k & 31) >> 3) << 4) | (c & 15);
      dst[(size_t)2 * 16384 + (((nt * 4 + bs) * 64) + l) * 8 + (k & 7)] = f2h(acc[q]);
    }
    if (bs == 0 && tid < HH) {
      float s = 0.f;
      for (int j = 0; j < HH; ++j) s += bm2[j] * h2f(WuLh[j * HH + tid]);
      ((float*)(ws + BC_OFF))[tid] = s;
    }
    __syncthreads();
  }

  // setup producers: publish
  if (b < 13) {
    __threadfence();
    __syncthreads();
    if (tid == 0)
      __hip_atomic_fetch_add(flag, 1, __ATOMIC_RELEASE, __HIP_MEMORY_SCOPE_AGENT);
  }

  // ================= all blocks: stage X fp32 + Xb fp16 (swizzled) ==========
  {
    const float4* nf4 = (const float4*)(node + (size_t)b * NN * HH);
    const int i2 = tid + 2048;
    const bool has2 = (i2 < NN * HH / 4);     // 2592 float4 total
    float4 v0 = nf4[tid];
    float4 v1 = nf4[tid + 1024];
    float4 v2 = has2 ? nf4[i2] : make_float4(0.f, 0.f, 0.f, 0.f);
#pragma unroll
    for (int k = 0; k < 3; ++k) {
      const int i = tid + k * 1024;
      if (k == 2 && !has2) break;
      const float4 v = (k == 0) ? v0 : (k == 1) ? v1 : v2;
      const int r = i >> 5, c = (i & 31) * 4;
      *(float4*)&X[r][c] = v;
      uint2 pv; pv.x = f2h2(v.x, v.y); pv.y = f2h2(v.z, v.w);
      *(uint2*)(Xb + swzu(r, c * 2)) = pv;
    }
    if (tid < (MPAD - NN) * 16) {   // zero pad rows 81..95
      const int r = NN + tid / 16, m = tid % 16;
      ushort8v z = {0,0,0,0,0,0,0,0};
      *(ushort8v*)(Xb + swzu(r, m * 16)) = z;
    }
  }

  // ================= wait for setup completion ==============================
  if (tid == 0) {
    while (__hip_atomic_load(flag, __ATOMIC_ACQUIRE, __HIP_MEMORY_SCOPE_AGENT) < 13)
      __builtin_amdgcn_s_sleep(8);
  }
  __syncthreads();

  // ---- post-flag: B-frag preload + csr/offs/bias staging ----
  const unsigned short* wpk = (const unsigned short*)ws;
  const int nt0 = wave & 7;
  const int mt0 = 3 * (wave >> 3);
  const int erow = (lane >> 4) * 4;
  const int ecol = lane & 15;
  const int C    = nt0 * 16 + ecol;

  f16x8 BA0[4], BA1[4];
  loadB(wpk, nt0, lane, BA0);
  loadB(wpk + 16384, nt0, lane, BA1);
  {
    const int* wofs = (const int*)(ws + OFFS_OFF);
    const int* wcsr = (const int*)(ws + CSR_OFF);
    const float* wbc = (const float*)(ws + BC_OFF);
    for (int i = tid; i < EE; i += 1024) csrL[i] = wcsr[i];
    if (tid < NN + 1) offsL[tid] = wofs[tid];
    if (tid < HH) {
      bias[0][tid] = bm1[tid];  bias[1][tid] = wbc[tid];
      bias[2][tid] = bu1[tid];  bias[3][tid] = bu2[tid];
      bias[4][tid] = gamma_[tid]; bias[5][tid] = beta_[tid];
    }
  }
  __syncthreads();

  // ---- GEMM A: P = Xb@Wm1t -> bufP ; Q' = Xb@Wm1b + bm1 -> bufQ ----
  {
    f32x4 accP[3], accQ[3];
#pragma unroll
    for (int mm = 0; mm < 3; ++mm) { accP[mm] = (f32x4)0.f; accQ[mm] = (f32x4)0.f; }
    gemm3x2(Xb, BA0, BA1, lane, mt0, accP, accQ);
#pragma unroll
    for (int mm = 0; mm < 3; ++mm)
#pragma unroll
      for (int rg = 0; rg < 4; ++rg) {
        const int R = (mt0 + mm) * 16 + erow + rg;
        const unsigned byte = swzu(R, C * 2);
        const bool ok = (R < NN);
        *(unsigned short*)(bufP + byte) = ok ? f2h(accP[mm][rg]) : (unsigned short)0;
        *(unsigned short*)(bufQ + byte) = ok ? f2h(accQ[mm][rg] + bias[0][C]) : (unsigned short)0;
      }
  }
  __syncthreads();

  // ---- edge aggregation, packed fp16 (x4 unrolled) ----
  {
    const int lb = lane * 4;
    for (int t = wave; t < NN; t += 16) {
      const unsigned qbyte = swzu(t, lb);
      const unsigned q = *(const unsigned*)(bufQ + qbyte);
      unsigned h = 0u, g = 0u;
      int e = offsL[t];
      const int o1 = offsL[t + 1];
      for (; e + 4 <= o1; e += 4) {
        const int s0 = csrL[e], s1 = csrL[e + 1], s2 = csrL[e + 2], s3 = csrL[e + 3];
        const unsigned p0 = *(const unsigned*)(bufP + swzu(s0, lb));
        const unsigned p1 = *(const unsigned*)(bufP + swzu(s1, lb));
        const unsigned p2 = *(const unsigned*)(bufP + swzu(s2, lb));
        const unsigned p3 = *(const unsigned*)(bufP + swzu(s3, lb));
        h = pk_add(h, pk_relu(pk_add(p0, q)));
        g = pk_add(g, pk_relu(pk_add(p1, q)));
        h = pk_add(h, pk_relu(pk_add(p2, q)));
        g = pk_add(g, pk_relu(pk_add(p3, q)));
      }
      for (; e < o1; ++e) {
        const int s = csrL[e];
        const unsigned pp = *(const unsigned*)(bufP + swzu(s, lb));
        h = pk_add(h, pk_relu(pk_add(pp, q)));
      }
      h = pk_add(h, g);
      *(unsigned*)(bufQ + qbyte) = h;
    }
  }
  __syncthreads();

  // ---- GEMM BC: T = Hsum@Wc ; U = Xb@Wu1t ; h2 -> bufP ----
  {
    f16x8 BW[4], BU[4];
    loadB(wpk + 2 * 16384, nt0, lane, BW);
    loadB(wpk + 3 * 16384, nt0, lane, BU);
    f32x4 accT[3], accU[3];
#pragma unroll
    for (int mm = 0; mm < 3; ++mm) { accT[mm] = (f32x4)0.f; accU[mm] = (f32x4)0.f; }
    gemm3_2A(bufQ, Xb, BW, BU, lane, mt0, accT, accU);
#pragma unroll
    for (int mm = 0; mm < 3; ++mm)
#pragma unroll
      for (int rg = 0; rg < 4; ++rg) {
        const int R = (mt0 + mm) * 16 + erow + rg;
        float v = 0.f;
        if (R < NN) {
          const int dg = offsL[R + 1] - offsL[R];
          const float inv = (dg > 0) ? 1.f / (float)dg : 1.f;
          const float sf  = (dg > 0) ? 1.f : 0.f;
          v = fmaxf(accU[mm][rg] + accT[mm][rg] * inv + sf * bias[1][C] + bias[2][C], 0.f);
        }
        *(unsigned short*)(bufP + swzu(R, C * 2)) = f2h(v);
      }
  }
  __syncthreads();

  // ---- GEMM D: x = X + h2@Wu2 + bu2 (in place into X fp32) ----
  {
    f16x8 BD[4];
    loadB(wpk + 5 * 16384, nt0, lane, BD);
    f32x4 acc[3];
#pragma unroll
    for (int mm = 0; mm < 3; ++mm) acc[mm] = (f32x4)0.f;
    gemm3(bufP, BD, lane, mt0, acc);
#pragma unroll
    for (int mm = 0; mm < 3; ++mm)
#pragma unroll
      for (int rg = 0; rg < 4; ++rg) {
        const int R = (mt0 + mm) * 16 + erow + rg;
        if (R < NN) X[R][C] += acc[mm][rg] + bias[3][C];
      }
  }
  __syncthreads();

  // ---- LayerNorm per row + store ----
  for (int r = wave; r < NN; r += 16) {
    const float x0 = X[r][lane], x1 = X[r][lane + 64];
    float s = x0 + x1;
#pragma unroll
    for (int off = 32; off; off >>= 1) s += __shfl_xor(s, off);
    const float mu = s * (1.f / 128.f);
    const float d0 = x0 - mu, d1 = x1 - mu;
    float v = d0 * d0 + d1 * d1;
#pragma unroll
    for (int off = 32; off; off >>= 1) v += __shfl_xor(v, off);
    const float rstd = rsqrtf(v * (1.f / 128.f) + 1e-5f);
    const size_t o = ((size_t)b * NN + r) * HH;
    out[o + lane]      = d0 * rstd * bias[4][lane]      + bias[5][lane];
    out[o + lane + 64] = d1 * rstd * bias[4][lane + 64] + bias[5][lane + 64];
  }
}

// =================== fallback: r11 two-kernel fp16 path ======================
__global__ __launch_bounds__(1024)
void setup_kernel(const float* __restrict__ Wm1, const float* __restrict__ Wm2,
                  const float* __restrict__ Wu1, const float* __restrict__ Wu2,
                  const float* __restrict__ bm2, const int* __restrict__ eidx,
                  char* __restrict__ ws) {
  __shared__ __align__(16) char arena[81920];
  const int tid = threadIdx.x;

  if (blockIdx.x < 8) {
    const int gid = blockIdx.x * 1024 + tid;
    const int lane = gid & 63;
    const int t = gid >> 6;
    const int ks = t & 3, nt = (t >> 2) & 7, mat = t >> 5;
    const float* src;
    int slot;
    if (mat == 0)      { src = Wm1;           slot = 0; }
    else if (mat == 1) { src = Wm1 + HH * HH; slot = 1; }
    else if (mat == 2) { src = Wu1;           slot = 3; }
    else               { src = Wu2;           slot = 5; }
    const int c = nt * 16 + (lane & 15);
    const int k0 = ks * 32 + (lane >> 4) * 8;
    f16x8 pv;
#pragma unroll
    for (int j = 0; j < 8; ++j) pv[j] = (_Float16)src[(k0 + j) * HH + c];
    *(f16x8*)((unsigned short*)ws + (size_t)slot * 16384 + (((nt * 4 + ks) * 64) + lane) * 8) = pv;
    return;
  }

  if (blockIdx.x == 8) {
    int* srcE  = (int*)arena;
    int* tgtE  = srcE + EE;
    int* rankS = tgtE + EE;
    int* cntC  = rankS + EE;
    int* tot   = cntC + NCHK * NN;
    int* scanS = tot + NN;
    int* wsumS = scanS + 128;
    int* offsS = wsumS + 2;
    for (int i = tid; i < NCHK * NN; i += 1024) cntC[i] = 0;
    for (int i = tid; i < 2 * EE; i += 1024) srcE[i] = eidx[i];
    __syncthreads();
    const int lane = tid & 63, wv = tid >> 6;
    for (int c = wv; c < NCHK; c += 16) {
      const int e = c * 64 + lane;
      const bool ok = (e < EE);
      const int t = ok ? tgtE[e] : -1;
      unsigned long long mymask = 0;
#pragma unroll
      for (int i = 0; i < 64; ++i) {
        const int ti = __shfl(t, i);
        const unsigned long long bal = __ballot(t == ti);
        if (i == lane) mymask = bal;
      }
      if (ok) {
        const int rank = __popcll(mymask & ((1ull << lane) - 1ull));
        rankS[e] = rank;
        if (rank == 0) cntC[c * NN + t] = __popcll(mymask);
      }
    }
    __syncthreads();
    if (tid < NN) {
      int s = 0;
#pragma unroll
      for (int c = 0; c < NCHK; ++c) s += cntC[c * NN + tid];
      tot[tid] = s;
    }
    __syncthreads();
    if (tid < 128) {
      const int l = tid & 63, w = tid >> 6;
      int inc = (tid < NN) ? tot[tid] : 0;
#pragma unroll
      for (int d = 1; d < 64; d <<= 1) {
        int u = __shfl_up(inc, d);
        if (l >= d) inc += u;
      }
      scanS[tid] = inc;
      if (l == 63) wsumS[w] = inc;
    }
    __syncthreads();
    if (tid < 128) {
      const int w = tid >> 6;
      const int inc = scanS[tid] + (w ? wsumS[0] : 0);
      if (tid < NN) offsS[tid] = inc - tot[tid];
      if (tid == NN - 1) offsS[NN] = inc;
    }
    __syncthreads();
    if (tid < NN) {
      int run = offsS[tid];
#pragma unroll
      for (int c = 0; c < NCHK; ++c) {
        const int tmp = cntC[c * NN + tid];
        cntC[c * NN + tid] = run;
        run += tmp;
      }
    }
    __syncthreads();
    int* wofs = (int*)(ws + OFFS_OFF);
    int* wcsr = (int*)(ws + CSR_OFF);
    for (int i = tid; i <= NN; i += 1024) wofs[i] = offsS[i];
    for (int e = tid; e < EE; e += 1024) {
      const int t = tgtE[e];
      wcsr[cntC[(e >> 6) * NN + t] + rankS[e]] = srcE[e];
    }
    return;
  }

  {
    const int bs = blockIdx.x - 9;
    float* WuL = (float*)arena;
    float* WmL = WuL + HH * HH;
    const float* Wu1b = Wu1 + HH * HH;
    float4* WuL4 = (float4*)WuL;
    const float4* src4 = (const float4*)Wu1b;
    for (int i = tid; i < HH * HH / 4; i += 1024) WuL4[i] = src4[i];
    const float4* wm4 = (const float4*)(Wm2 + bs * 32 * HH);
    float4* WmL4 = (float4*)WmL;
    if (tid < 32 * HH / 4) WmL4[tid] = wm4[tid];
    __syncthreads();
    const int kk = tid >> 5;
    const int k  = bs * 32 + kk;
    const int cg = tid & 31;
    f32x4 acc = (f32x4)0.f;
    for (int j = 0; j < HH; ++j) {
      const float a = WmL[kk * HH + j];
      const float4 w = WuL4[j * 32 + cg];
      acc[0] += a * w.x; acc[1] += a * w.y; acc[2] += a * w.z; acc[3] += a * w.w;
    }
    unsigned short* dst = (unsigned short*)ws;
#pragma unroll
    for (int q = 0; q < 4; ++q) {
      const int c = cg * 4 + q;
      const int nt = c >> 4;
      const int l = (((k & 31) >> 3) << 4) | (c & 15);
      dst[(size_t)2 * 16384 + (((nt * 4 + bs) * 64) + l) * 8 + (k & 7)] = f2h(acc[q]);
    }
    if (bs == 0 && tid < HH) {
      float s = 0.f;
      for (int j = 0; j < HH; ++j) s += bm2[j] * WuL[j * HH + tid];
      ((float*)(ws + BC_OFF))[tid] = s;
    }
  }
}

__global__ __launch_bounds__(1024, 4)
void mpnn_fp16_kernel(const float* __restrict__ node,
                      const float* __restrict__ bm1,
                      const float* __restrict__ bu1, const float* __restrict__ bu2,
                      const float* __restrict__ gamma_, const float* __restrict__ beta_,
                      const char* __restrict__ ws,
                      float* __restrict__ out) {
  __shared__ float X[NN][HH];
  __shared__ unsigned short XbS[MPAD * HH];
  __shared__ unsigned short bufPS[MPAD * HH];
  __shared__ unsigned short bufQS[MPAD * HH];
  __shared__ int   csrL[EE];
  __shared__ int   offsL[NN + 1];
  __shared__ float bias[6][HH];
  char* Xb   = (char*)XbS;
  char* bufP = (char*)bufPS;
  char* bufQ = (char*)bufQS;

  const int tid  = threadIdx.x;
  const int lane = tid & 63;
  const int wave = tid >> 6;
  const int b    = blockIdx.x;

  const unsigned short* wpk = (const unsigned short*)ws;
  const int* wofs = (const int*)(ws + OFFS_OFF);
  const int* wcsr = (const int*)(ws + CSR_OFF);
  const float* wbc = (const float*)(ws + BC_OFF);

  const int nt0 = wave & 7;
  const int mt0 = 3 * (wave >> 3);
  const int erow = (lane >> 4) * 4;
  const int ecol = lane & 15;
  const int C    = nt0 * 16 + ecol;

  f16x8 BA0[4], BA1[4];
  loadB(wpk, nt0, lane, BA0);
  loadB(wpk + 16384, nt0, lane, BA1);

  {
    const float4* nf4 = (const float4*)(node + (size_t)b * NN * HH);
    const int i2 = tid + 2048;
    const bool has2 = (i2 < NN * HH / 4);
    float4 v0 = nf4[tid];
    float4 v1 = nf4[tid + 1024];
    float4 v2 = has2 ? nf4[i2] : make_float4(0.f, 0.f, 0.f, 0.f);
#pragma unroll
    for (int k = 0; k < 3; ++k) {
      const int i = tid + k * 1024;
      if (k == 2 && !has2) break;
      const float4 v = (k == 0) ? v0 : (k == 1) ? v1 : v2;
      const int r = i >> 5, c = (i & 31) * 4;
      *(float4*)&X[r][c] = v;
      uint2 pv; pv.x = f2h2(v.x, v.y); pv.y = f2h2(v.z, v.w);
      *(uint2*)(Xb + swzu(r, c * 2)) = pv;
    }
    if (tid < (MPAD - NN) * 16) {
      const int r = NN + tid / 16, m = tid % 16;
      ushort8v z = {0,0,0,0,0,0,0,0};
      *(ushort8v*)(Xb + swzu(r, m * 16)) = z;
    }
    for (int i = tid; i < EE; i += 1024) csrL[i] = wcsr[i];
    if (tid < NN + 1) offsL[tid] = wofs[tid];
    if (tid < HH) {
      bias[0][tid] = bm1[tid];  bias[1][tid] = wbc[tid];
      bias[2][tid] = bu1[tid];  bias[3][tid] = bu2[tid];
      bias[4][tid] = gamma_[tid]; bias[5][tid] = beta_[tid];
    }
  }
  __syncthreads();

  {
    f32x4 accP[3], accQ[3];
#pragma unroll
    for (int mm = 0; mm < 3; ++mm) { accP[mm] = (f32x4)0.f; accQ[mm] = (f32x4)0.f; }
    gemm3x2(Xb, BA0, BA1, lane, mt0, accP, accQ);
#pragma unroll
    for (int mm = 0; mm < 3; ++mm)
#pragma unroll
      for (int rg = 0; rg < 4; ++rg) {
        const int R = (mt0 + mm) * 16 + erow + rg;
        const unsigned byte = swzu(R, C * 2);
        const bool ok = (R < NN);
        *(unsigned short*)(bufP + byte) = ok ? f2h(accP[mm][rg]) : (unsigned short)0;
        *(unsigned short*)(bufQ + byte) = ok ? f2h(accQ[mm][rg] + bias[0][C]) : (unsigned short)0;
      }
  }
  __syncthreads();

  {
    const int lb = lane * 4;
    for (int t = wave; t < NN; t += 16) {
      const unsigned qbyte = swzu(t, lb);
      const unsigned q = *(const unsigned*)(bufQ + qbyte);
      unsigned h = 0u, g = 0u;
      int e = offsL[t];
      const int o1 = offsL[t + 1];
      for (; e + 4 <= o1; e += 4) {
        const int s0 = csrL[e], s1 = csrL[e + 1], s2 = csrL[e + 2], s3 = csrL[e + 3];
        const unsigned p0 = *(const unsigned*)(bufP + swzu(s0, lb));
        const unsigned p1 = *(const unsigned*)(bufP + swzu(s1, lb));
        const unsigned p2 = *(const unsigned*)(bufP + swzu(s2, lb));
        const unsigned p3 = *(const unsigned*)(bufP + swzu(s3, lb));
        h = pk_add(h, pk_relu(pk_add(p0, q)));
        g = pk_add(g, pk_relu(pk_add(p1, q)));
        h = pk_add(h, pk_relu(pk_add(p2, q)));
        g = pk_add(g, pk_relu(pk_add(p3, q)));
      }
      for (; e < o1; ++e) {
        const int s = csrL[e];
        const unsigned pp = *(const unsigned*)(bufP + swzu(s, lb));
        h = pk_add(h, pk_relu(pk_add(pp, q)));
      }
      h = pk_add(h, g);
      *(unsigned*)(bufQ + qbyte) = h;
    }
  }
  __syncthreads();

  {
    f16x8 BW[4], BU[4];
    loadB(wpk + 2 * 16384, nt0, lane, BW);
    loadB(wpk + 3 * 16384, nt0, lane, BU);
    f32x4 accT[3], accU[3];
#pragma unroll
    for (int mm = 0; mm < 3; ++mm) { accT[mm] = (f32x4)0.f; accU[mm] = (f32x4)0.f; }
    gemm3_2A(bufQ, Xb, BW, BU, lane, mt0, accT, accU);
#pragma unroll
    for (int mm = 0; mm < 3; ++mm)
#pragma unroll
      for (int rg = 0; rg < 4; ++rg) {
        const int R = (mt0 + mm) * 16 + erow + rg;
        float v = 0.f;
        if (R < NN) {
          const int dg = offsL[R + 1] - offsL[R];
          const float inv = (dg > 0) ? 1.f / (float)dg : 1.f;
          const float sf  = (dg > 0) ? 1.f : 0.f;
          v = fmaxf(accU[mm][rg] + accT[mm][rg] * inv + sf * bias[1][C] + bias[2][C], 0.f);
        }
        *(unsigned short*)(bufP + swzu(R, C * 2)) = f2h(v);
      }
  }
  __syncthreads();

  {
    f16x8 BD[4];
    loadB(wpk + 5 * 16384, nt0, lane, BD);
    f32x4 acc[3];
#pragma unroll
    for (int mm = 0; mm < 3; ++mm) acc[mm] = (f32x4)0.f;
    gemm3(bufP, BD, lane, mt0, acc);
#pragma unroll
    for (int mm = 0; mm < 3; ++mm)
#pragma unroll
      for (int rg = 0; rg < 4; ++rg) {
        const int R = (mt0 + mm) * 16 + erow + rg;
        if (R < NN) X[R][C] += acc[mm][rg] + bias[3][C];
      }
  }
  __syncthreads();

  for (int r = wave; r < NN; r += 16) {
    const float x0 = X[r][lane], x1 = X[r][lane + 64];
    float s = x0 + x1;
#pragma unroll
    for (int off = 32; off; off >>= 1) s += __shfl_xor(s, off);
    const float mu = s * (1.f / 128.f);
    const float d0 = x0 - mu, d1 = x1 - mu;
    float v = d0 * d0 + d1 * d1;
#pragma unroll
    for (int off = 32; off; off >>= 1) v += __shfl_xor(v, off);
    const float rstd = rsqrtf(v * (1.f / 128.f) + 1e-5f);
    const size_t o = ((size_t)b * NN + r) * HH;
    out[o + lane]      = d0 * rstd * bias[4][lane]      + bias[5][lane];
    out[o + lane + 64] = d1 * rstd * bias[4][lane + 64] + bias[5][lane + 64];
  }
}

extern "C" void kernel_launch(void* const* d_in, const int* in_sizes, int n_in,
                              void* d_out, int out_size, void* d_ws, size_t ws_size,
                              hipStream_t stream) {
  (void)in_sizes; (void)n_in; (void)out_size;
  const float* node  = (const float*)d_in[0];
  const int*   eidx  = (const int*)  d_in[1];
  const float* Wm1   = (const float*)d_in[2];
  const float* bm1   = (const float*)d_in[3];
  const float* Wm2   = (const float*)d_in[4];
  const float* bm2   = (const float*)d_in[5];
  const float* Wu1   = (const float*)d_in[6];
  const float* bu1   = (const float*)d_in[7];
  const float* Wu2   = (const float*)d_in[8];
  const float* bu2   = (const float*)d_in[9];
  const float* gamma_= (const float*)d_in[10];
  const float* beta_ = (const float*)d_in[11];
  float* outp = (float*)d_out;
  char* ws = (char*)d_ws;

  if (ws_size >= (size_t)WS_NEED) {
    hipMemsetAsync(ws + FLAG_OFF, 0, 4, stream);   // reset flag each call
    hipLaunchKernelGGL(mpnn_flag_kernel, dim3(256), dim3(1024), 0, stream,
                       node, eidx, Wm1, bm1, Wm2, bm2, Wu1, bu1, Wu2, bu2,
                       gamma_, beta_, ws, outp);
  } else {
    hipLaunchKernelGGL(setup_kernel, dim3(13), dim3(1024), 0, stream,
                       Wm1, Wm2, Wu1, Wu2, bm2, eidx, ws);
    hipLaunchKernelGGL(mpnn_fp16_kernel, dim3(256), dim3(1024), 0, stream,
                       node, bm1, bu1, bu2, gamma_, beta_, ws, outp);
  }
}

// Round 14
// 39.259 us; speedup vs baseline: 3.8210x; 2.9346x over previous
//
#include <hip/hip_runtime.h>

// Fused MPNN layer, B=256, N=81, H=128, E=1620 — MFMA fp16, two-kernel (r11)
// + uchar-packed CSR (4 edge indices per ds_read in the agg hot loop).
//   P = X @ Wm1[:H],  Q' = X @ Wm1[H:] + bm1
//   Hsum[t] = sum_{e: tgt=t} relu(P[src_e] + Q'[t])
//   Folded:  agg@Wu1b = (Hsum@Wc)*inv_deg + 1[deg>0]*bc,  Wc=Wm2@Wu1b, bc=bm2@Wu1b
//   h2 = relu(X@Wu1t + (Hsum@Wc)*inv + s*bc + bu1)
//   x  = X + h2 @ Wu2 + bu2 ;  out = LayerNorm(x)*gamma + beta
// Setup (grid 13 x 1024): blocks 0-7 pack weights to fp16 frag order; block 8
//   ballot-CSR (uchar); blocks 9-12 Wc + bc.
// Main (grid 256, 1024 thr = 16 waves): whole layer per batch in LDS.

#define NN 81
#define HH 128
#define EE 1620
#define NCHK 26                         // ceil(EE/64)
#define MPAD 96
#define WB_BYTES 196608                 // 6 * 16384 ushorts (slot4 unused)
#define OFFS_OFF (WB_BYTES)             // int offs[82]
#define CSR_OFF  (OFFS_OFF + 82 * 4)    // uchar csr[1620] (padded to 1624)
#define BC_OFF   (CSR_OFF + 1624)       // float bc[128]
#define WS_NEED  (BC_OFF + HH * 4)

typedef _Float16 f16x8 __attribute__((ext_vector_type(8)));
typedef __fp16   h16x2 __attribute__((ext_vector_type(2)));
typedef __attribute__((ext_vector_type(8))) unsigned short ushort8v;
typedef __attribute__((ext_vector_type(4))) float f32x4;

__device__ __forceinline__ unsigned short f2h(float f) {
  union { _Float16 h; unsigned short u; } v; v.h = (_Float16)f; return v.u;
}
__device__ __forceinline__ float h2f(unsigned short u) {
  union { unsigned short u; _Float16 h; } v; v.u = u; return (float)v.h;
}
__device__ __forceinline__ unsigned f2h2(float x, float y) {   // v_cvt_pkrtz
  union { h16x2 h; unsigned u; } v;
  v.h = __builtin_amdgcn_cvt_pkrtz(x, y);
  return v.u;
}
__device__ __forceinline__ unsigned pk_add(unsigned a, unsigned b) {
  unsigned r; asm("v_pk_add_f16 %0, %1, %2" : "=v"(r) : "v"(a), "v"(b)); return r;
}
__device__ __forceinline__ unsigned pk_relu(unsigned a) {
  unsigned r; asm("v_pk_max_f16 %0, %1, %2" : "=v"(r) : "v"(a), "v"(0u)); return r;
}
__device__ __forceinline__ unsigned swzu(int r, int laneb) {
  return ((unsigned)(r * 256 + laneb)) ^ ((unsigned)((r & 7) << 4));
}

// ---------------- setup kernel ------------------------------------------------
__global__ __launch_bounds__(1024)
void setup_kernel(const float* __restrict__ Wm1, const float* __restrict__ Wm2,
                  const float* __restrict__ Wu1, const float* __restrict__ Wu2,
                  const float* __restrict__ bm2, const int* __restrict__ eidx,
                  char* __restrict__ ws) {
  __shared__ __align__(16) char arena[81920];
  const int tid = threadIdx.x;

  if (blockIdx.x < 8) {
    // pack 4 source mats to fp16 frag order: 4 mats * 8 nt * 4 ks * 64 lanes
    const int gid = blockIdx.x * 1024 + tid;
    const int lane = gid & 63;
    const int t = gid >> 6;
    const int ks = t & 3, nt = (t >> 2) & 7, mat = t >> 5;
    const float* src;
    int slot;
    if (mat == 0)      { src = Wm1;           slot = 0; }
    else if (mat == 1) { src = Wm1 + HH * HH; slot = 1; }
    else if (mat == 2) { src = Wu1;           slot = 3; }
    else               { src = Wu2;           slot = 5; }
    const int c = nt * 16 + (lane & 15);
    const int k0 = ks * 32 + (lane >> 4) * 8;
    f16x8 pv;
#pragma unroll
    for (int j = 0; j < 8; ++j) pv[j] = (_Float16)src[(k0 + j) * HH + c];
    *(f16x8*)((unsigned short*)ws + (size_t)slot * 16384 + (((nt * 4 + ks) * 64) + lane) * 8) = pv;
    return;
  }

  if (blockIdx.x == 8) {
    // deterministic CSR via ballot match-masks (stable counting sort), uchar out
    int* srcE  = (int*)arena;            // EE
    int* tgtE  = srcE + EE;              // EE
    int* rankS = tgtE + EE;              // EE
    int* cntC  = rankS + EE;             // NCHK*NN
    int* tot   = cntC + NCHK * NN;       // NN
    int* scanS = tot + NN;               // 128
    int* wsumS = scanS + 128;            // 2
    int* offsS = wsumS + 2;              // NN+1
    for (int i = tid; i < NCHK * NN; i += 1024) cntC[i] = 0;
    for (int i = tid; i < 2 * EE; i += 1024) srcE[i] = eidx[i];
    __syncthreads();
    const int lane = tid & 63, wv = tid >> 6;
    for (int c = wv; c < NCHK; c += 16) {
      const int e = c * 64 + lane;
      const bool ok = (e < EE);
      const int t = ok ? tgtE[e] : -1;
      unsigned long long mymask = 0;
#pragma unroll
      for (int i = 0; i < 64; ++i) {
        const int ti = __shfl(t, i);
        const unsigned long long bal = __ballot(t == ti);
        if (i == lane) mymask = bal;
      }
      if (ok) {
        const int rank = __popcll(mymask & ((1ull << lane) - 1ull));
        rankS[e] = rank;
        if (rank == 0) cntC[c * NN + t] = __popcll(mymask);
      }
    }
    __syncthreads();
    if (tid < NN) {
      int s = 0;
#pragma unroll
      for (int c = 0; c < NCHK; ++c) s += cntC[c * NN + tid];
      tot[tid] = s;
    }
    __syncthreads();
    if (tid < 128) {
      const int l = tid & 63, w = tid >> 6;
      int inc = (tid < NN) ? tot[tid] : 0;
#pragma unroll
      for (int d = 1; d < 64; d <<= 1) {
        int u = __shfl_up(inc, d);
        if (l >= d) inc += u;
      }
      scanS[tid] = inc;
      if (l == 63) wsumS[w] = inc;
    }
    __syncthreads();
    if (tid < 128) {
      const int w = tid >> 6;
      const int inc = scanS[tid] + (w ? wsumS[0] : 0);
      if (tid < NN) offsS[tid] = inc - tot[tid];
      if (tid == NN - 1) offsS[NN] = inc;
    }
    __syncthreads();
    if (tid < NN) {
      int run = offsS[tid];
#pragma unroll
      for (int c = 0; c < NCHK; ++c) {
        const int tmp = cntC[c * NN + tid];
        cntC[c * NN + tid] = run;
        run += tmp;
      }
    }
    __syncthreads();
    int* wofs = (int*)(ws + OFFS_OFF);
    unsigned char* wcsr = (unsigned char*)(ws + CSR_OFF);
    for (int i = tid; i <= NN; i += 1024) wofs[i] = offsS[i];
    for (int e = tid; e < EE; e += 1024) {
      const int t = tgtE[e];
      wcsr[cntC[(e >> 6) * NN + t] + rankS[e]] = (unsigned char)srcE[e];
    }
    return;
  }

  // blocks 9-12: Wc = Wm2 @ Wu1b, rows [32*bs,32*bs+32); pack slot 2; bs0: bc
  {
    const int bs = blockIdx.x - 9;
    float* WuL = (float*)arena;
    float* WmL = WuL + HH * HH;
    const float* Wu1b = Wu1 + HH * HH;
    float4* WuL4 = (float4*)WuL;
    const float4* src4 = (const float4*)Wu1b;
    for (int i = tid; i < HH * HH / 4; i += 1024) WuL4[i] = src4[i];
    const float4* wm4 = (const float4*)(Wm2 + bs * 32 * HH);
    float4* WmL4 = (float4*)WmL;
    if (tid < 32 * HH / 4) WmL4[tid] = wm4[tid];
    __syncthreads();
    const int kk = tid >> 5;
    const int k  = bs * 32 + kk;
    const int cg = tid & 31;
    f32x4 acc = (f32x4)0.f;
    for (int j = 0; j < HH; ++j) {
      const float a = WmL[kk * HH + j];
      const float4 w = WuL4[j * 32 + cg];
      acc[0] += a * w.x; acc[1] += a * w.y; acc[2] += a * w.z; acc[3] += a * w.w;
    }
    unsigned short* dst = (unsigned short*)ws;
#pragma unroll
    for (int q = 0; q < 4; ++q) {
      const int c = cg * 4 + q;
      const int nt = c >> 4;
      const int l = (((k & 31) >> 3) << 4) | (c & 15);
      dst[(size_t)2 * 16384 + (((nt * 4 + bs) * 64) + l) * 8 + (k & 7)] = f2h(acc[q]);
    }
    if (bs == 0 && tid < HH) {
      float s = 0.f;
      for (int j = 0; j < HH; ++j) s += bm2[j] * WuL[j * HH + tid];
      ((float*)(ws + BC_OFF))[tid] = s;
    }
  }
}

// ---------------- MFMA helpers (fp16, per wave: 3 M-tiles x 1 N-tile) --------
__device__ __forceinline__ void loadB(const unsigned short* Wp, int nt0, int lane,
                                      f16x8 (&Bf)[4]) {
#pragma unroll
  for (int ks = 0; ks < 4; ++ks)
    Bf[ks] = *(const f16x8*)(Wp + ((nt0 * 4 + ks) * 64 + lane) * 8);
}

__device__ __forceinline__ void gemm3(const char* Ab, const f16x8 (&Bf)[4],
                                      int lane, int mt0, f32x4 (&acc)[3]) {
  const int rl = lane & 15;
  const int kb = (lane >> 4) * 16;
  const unsigned swz = (unsigned)((rl & 7) << 4);
#pragma unroll
  for (int ks = 0; ks < 4; ++ks)
#pragma unroll
    for (int mm = 0; mm < 3; ++mm) {
      const int r = (mt0 + mm) * 16 + rl;
      const unsigned byte = (unsigned)(r * 256) + (((unsigned)(ks * 64 + kb)) ^ swz);
      f16x8 a = *(const f16x8*)(Ab + byte);
      acc[mm] = __builtin_amdgcn_mfma_f32_16x16x32_f16(a, Bf[ks], acc[mm], 0, 0, 0);
    }
}

__device__ __forceinline__ void gemm3x2(const char* Ab,
                                        const f16x8 (&B0)[4], const f16x8 (&B1)[4],
                                        int lane, int mt0,
                                        f32x4 (&a0)[3], f32x4 (&a1)[3]) {
  const int rl = lane & 15;
  const int kb = (lane >> 4) * 16;
  const unsigned swz = (unsigned)((rl & 7) << 4);
#pragma unroll
  for (int ks = 0; ks < 4; ++ks)
#pragma unroll
    for (int mm = 0; mm < 3; ++mm) {
      const int r = (mt0 + mm) * 16 + rl;
      const unsigned byte = (unsigned)(r * 256) + (((unsigned)(ks * 64 + kb)) ^ swz);
      f16x8 a = *(const f16x8*)(Ab + byte);
      a0[mm] = __builtin_amdgcn_mfma_f32_16x16x32_f16(a, B0[ks], a0[mm], 0, 0, 0);
      a1[mm] = __builtin_amdgcn_mfma_f32_16x16x32_f16(a, B1[ks], a1[mm], 0, 0, 0);
    }
}

__device__ __forceinline__ void gemm3_2A(const char* A0, const char* A1,
                                         const f16x8 (&B0)[4], const f16x8 (&B1)[4],
                                         int lane, int mt0,
                                         f32x4 (&a0)[3], f32x4 (&a1)[3]) {
  const int rl = lane & 15;
  const int kb = (lane >> 4) * 16;
  const unsigned swz = (unsigned)((rl & 7) << 4);
#pragma unroll
  for (int ks = 0; ks < 4; ++ks)
#pragma unroll
    for (int mm = 0; mm < 3; ++mm) {
      const int r = (mt0 + mm) * 16 + rl;
      const unsigned byte = (unsigned)(r * 256) + (((unsigned)(ks * 64 + kb)) ^ swz);
      f16x8 x0 = *(const f16x8*)(A0 + byte);
      a0[mm] = __builtin_amdgcn_mfma_f32_16x16x32_f16(x0, B0[ks], a0[mm], 0, 0, 0);
      f16x8 x1 = *(const f16x8*)(A1 + byte);
      a1[mm] = __builtin_amdgcn_mfma_f32_16x16x32_f16(x1, B1[ks], a1[mm], 0, 0, 0);
    }
}

__global__ __launch_bounds__(1024)
void mpnn_fp16_kernel(const float* __restrict__ node,
                      const float* __restrict__ bm1,
                      const float* __restrict__ bu1, const float* __restrict__ bu2,
                      const float* __restrict__ gamma_, const float* __restrict__ beta_,
                      const char* __restrict__ ws,
                      float* __restrict__ out) {
  __shared__ float X[NN][HH];                 // fp32 for residual + LN
  __shared__ unsigned short XbS[MPAD * HH];   // swizzled fp16
  __shared__ unsigned short bufPS[MPAD * HH]; // P -> h2
  __shared__ unsigned short bufQS[MPAD * HH]; // Q' -> Hsum
  __shared__ __align__(4) unsigned char csrL[1624];   // uchar CSR
  __shared__ int   offsL[NN + 1];
  __shared__ float bias[6][HH];               // bm1,bc,bu1,bu2,gamma,beta
  char* Xb   = (char*)XbS;
  char* bufP = (char*)bufPS;
  char* bufQ = (char*)bufQS;

  const int tid  = threadIdx.x;
  const int lane = tid & 63;
  const int wave = tid >> 6;     // 0..15
  const int b    = blockIdx.x;

  const unsigned short* wpk = (const unsigned short*)ws;
  const int* wofs = (const int*)(ws + OFFS_OFF);
  const unsigned* wcsr4 = (const unsigned*)(ws + CSR_OFF);
  const float* wbc = (const float*)(ws + BC_OFF);

  // wave tile map: 16 waves = 8 N-tiles x 2 M-halves (3 M-tiles each)
  const int nt0 = wave & 7;
  const int mt0 = 3 * (wave >> 3);
  const int erow = (lane >> 4) * 4;
  const int ecol = lane & 15;
  const int C    = nt0 * 16 + ecol;

  // ---- GEMM-A B-frag preload (global, independent of LDS staging) ----
  f16x8 BA0[4], BA1[4];
  loadB(wpk, nt0, lane, BA0);
  loadB(wpk + 16384, nt0, lane, BA1);

  // ---- stage: X fp32 + Xb fp16 (swizzled), csr/offs, biases ----
  {
    const float4* nf4 = (const float4*)(node + (size_t)b * NN * HH);
    const int i2 = tid + 2048;
    const bool has2 = (i2 < NN * HH / 4);     // 2592 float4 total
    float4 v0 = nf4[tid];
    float4 v1 = nf4[tid + 1024];
    float4 v2 = has2 ? nf4[i2] : make_float4(0.f, 0.f, 0.f, 0.f);
#pragma unroll
    for (int k = 0; k < 3; ++k) {
      const int i = tid + k * 1024;
      if (k == 2 && !has2) break;
      const float4 v = (k == 0) ? v0 : (k == 1) ? v1 : v2;
      const int r = i >> 5, c = (i & 31) * 4;
      *(float4*)&X[r][c] = v;
      uint2 pv; pv.x = f2h2(v.x, v.y); pv.y = f2h2(v.z, v.w);
      *(uint2*)(Xb + swzu(r, c * 2)) = pv;
    }
    if (tid < (MPAD - NN) * 16) {   // zero pad rows 81..95
      const int r = NN + tid / 16, m = tid % 16;
      ushort8v z = {0,0,0,0,0,0,0,0};
      *(ushort8v*)(Xb + swzu(r, m * 16)) = z;
    }
    if (tid < 406) ((unsigned*)csrL)[tid] = wcsr4[tid];   // 1624 B as 406 uints
    if (tid < NN + 1) offsL[tid] = wofs[tid];
    if (tid < HH) {
      bias[0][tid] = bm1[tid];  bias[1][tid] = wbc[tid];
      bias[2][tid] = bu1[tid];  bias[3][tid] = bu2[tid];
      bias[4][tid] = gamma_[tid]; bias[5][tid] = beta_[tid];
    }
  }
  __syncthreads();

  // ---- GEMM A: P = Xb@Wm1t -> bufP ; Q' = Xb@Wm1b + bm1 -> bufQ ----
  {
    f32x4 accP[3], accQ[3];
#pragma unroll
    for (int mm = 0; mm < 3; ++mm) { accP[mm] = (f32x4)0.f; accQ[mm] = (f32x4)0.f; }
    gemm3x2(Xb, BA0, BA1, lane, mt0, accP, accQ);
#pragma unroll
    for (int mm = 0; mm < 3; ++mm)
#pragma unroll
      for (int rg = 0; rg < 4; ++rg) {
        const int R = (mt0 + mm) * 16 + erow + rg;
        const unsigned byte = swzu(R, C * 2);
        const bool ok = (R < NN);
        *(unsigned short*)(bufP + byte) = ok ? f2h(accP[mm][rg]) : (unsigned short)0;
        *(unsigned short*)(bufQ + byte) = ok ? f2h(accQ[mm][rg] + bias[0][C]) : (unsigned short)0;
      }
  }
  __syncthreads();

  // ---- edge aggregation, packed fp16, uchar CSR (4 idx per load) ----
  {
    const int lb = lane * 4;
    for (int t = wave; t < NN; t += 16) {
      const unsigned qbyte = swzu(t, lb);
      const unsigned q = *(const unsigned*)(bufQ + qbyte);
      unsigned h = 0u, g = 0u;
      int e = offsL[t];
      const int o1 = offsL[t + 1];
      // head: to 4-alignment
      for (; e < o1 && (e & 3); ++e) {
        const int s = csrL[e];
        const unsigned pp = *(const unsigned*)(bufP + swzu(s, lb));
        h = pk_add(h, pk_relu(pk_add(pp, q)));
      }
      // body: 4 indices per uint load
      for (; e + 4 <= o1; e += 4) {
        const unsigned cw = *(const unsigned*)(csrL + e);
        const int s0 = cw & 0xff, s1 = (cw >> 8) & 0xff;
        const int s2 = (cw >> 16) & 0xff, s3 = cw >> 24;
        const unsigned p0 = *(const unsigned*)(bufP + swzu(s0, lb));
        const unsigned p1 = *(const unsigned*)(bufP + swzu(s1, lb));
        const unsigned p2 = *(const unsigned*)(bufP + swzu(s2, lb));
        const unsigned p3 = *(const unsigned*)(bufP + swzu(s3, lb));
        h = pk_add(h, pk_relu(pk_add(p0, q)));
        g = pk_add(g, pk_relu(pk_add(p1, q)));
        h = pk_add(h, pk_relu(pk_add(p2, q)));
        g = pk_add(g, pk_relu(pk_add(p3, q)));
      }
      // tail
      for (; e < o1; ++e) {
        const int s = csrL[e];
        const unsigned pp = *(const unsigned*)(bufP + swzu(s, lb));
        h = pk_add(h, pk_relu(pk_add(pp, q)));
      }
      h = pk_add(h, g);
      *(unsigned*)(bufQ + qbyte) = h;
    }
  }
  __syncthreads();

  // ---- GEMM BC: T = Hsum@Wc ; U = Xb@Wu1t ;
  //      h2 = relu(U + T*inv_deg + s*bc + bu1) -> bufP ----
  {
    f16x8 BW[4], BU[4];
    loadB(wpk + 2 * 16384, nt0, lane, BW);
    loadB(wpk + 3 * 16384, nt0, lane, BU);
    f32x4 accT[3], accU[3];
#pragma unroll
    for (int mm = 0; mm < 3; ++mm) { accT[mm] = (f32x4)0.f; accU[mm] = (f32x4)0.f; }
    gemm3_2A(bufQ, Xb, BW, BU, lane, mt0, accT, accU);
#pragma unroll
    for (int mm = 0; mm < 3; ++mm)
#pragma unroll
      for (int rg = 0; rg < 4; ++rg) {
        const int R = (mt0 + mm) * 16 + erow + rg;
        float v = 0.f;
        if (R < NN) {
          const int dg = offsL[R + 1] - offsL[R];
          const float inv = (dg > 0) ? 1.f / (float)dg : 1.f;
          const float sf  = (dg > 0) ? 1.f : 0.f;
          v = fmaxf(accU[mm][rg] + accT[mm][rg] * inv + sf * bias[1][C] + bias[2][C], 0.f);
        }
        *(unsigned short*)(bufP + swzu(R, C * 2)) = f2h(v);
      }
  }
  __syncthreads();

  // ---- GEMM D: x = X + h2@Wu2 + bu2 (in place into X fp32) ----
  {
    f16x8 BD[4];
    loadB(wpk + 5 * 16384, nt0, lane, BD);
    f32x4 acc[3];
#pragma unroll
    for (int mm = 0; mm < 3; ++mm) acc[mm] = (f32x4)0.f;
    gemm3(bufP, BD, lane, mt0, acc);
#pragma unroll
    for (int mm = 0; mm < 3; ++mm)
#pragma unroll
      for (int rg = 0; rg < 4; ++rg) {
        const int R = (mt0 + mm) * 16 + erow + rg;
        if (R < NN) X[R][C] += acc[mm][rg] + bias[3][C];
      }
  }
  __syncthreads();

  // ---- LayerNorm per row + store ----
  for (int r = wave; r < NN; r += 16) {
    const float x0 = X[r][lane], x1 = X[r][lane + 64];
    float s = x0 + x1;
#pragma unroll
    for (int off = 32; off; off >>= 1) s += __shfl_xor(s, off);
    const float mu = s * (1.f / 128.f);
    const float d0 = x0 - mu, d1 = x1 - mu;
    float v = d0 * d0 + d1 * d1;
#pragma unroll
    for (int off = 32; off; off >>= 1) v += __shfl_xor(v, off);
    const float rstd = rsqrtf(v * (1.f / 128.f) + 1e-5f);
    const size_t o = ((size_t)b * NN + r) * HH;
    out[o + lane]      = d0 * rstd * bias[4][lane]      + bias[5][lane];
    out[o + lane + 64] = d1 * rstd * bias[4][lane + 64] + bias[5][lane + 64];
  }
}

// ================= fp32 fallback (known-good, used only if ws too small) =====
__device__ __forceinline__ void gemm_acc_f32(const float (*A)[HH], const float* __restrict__ Wg,
                                             int c, int row0, int nr, float (&acc)[41]) {
  float w[8];
#pragma unroll
  for (int j = 0; j < 8; ++j) w[j] = Wg[j * HH + c];
  for (int k0 = 0; k0 < HH; k0 += 8) {
    float wn[8];
    if (k0 + 8 < HH) {
#pragma unroll
      for (int j = 0; j < 8; ++j) wn[j] = Wg[(k0 + 8 + j) * HH + c];
    }
#pragma unroll
    for (int i = 0; i < 41; ++i) {
      if (i < nr) {
        const float4 a0 = *(const float4*)&A[row0 + i][k0];
        const float4 a1 = *(const float4*)&A[row0 + i][k0 + 4];
        acc[i] += a0.x * w[0] + a0.y * w[1] + a0.z * w[2] + a0.w * w[3]
                + a1.x * w[4] + a1.y * w[5] + a1.z * w[6] + a1.w * w[7];
      }
    }
#pragma unroll
    for (int j = 0; j < 8; ++j) w[j] = wn[j];
  }
}

__global__ __launch_bounds__(256, 1)
void mpnn_fused_kernel(const float* __restrict__ node, const int* __restrict__ eidx,
                       const float* __restrict__ Wm1, const float* __restrict__ bm1,
                       const float* __restrict__ Wm2, const float* __restrict__ bm2,
                       const float* __restrict__ Wu1, const float* __restrict__ bu1,
                       const float* __restrict__ Wu2, const float* __restrict__ bu2,
                       const float* __restrict__ gamma_, const float* __restrict__ beta_,
                       float* __restrict__ out) {
  __shared__ float X[NN][HH];
  __shared__ float Pb[NN][HH];
  __shared__ float Qb[NN][HH];
  __shared__ int   edg[2 * EE];
  __shared__ int   csr[EE];
  __shared__ int   offs[NN + 1];
  __shared__ int   cnt3[3][NN];
  __shared__ int   base3[3][NN];
  __shared__ float biases[6][HH];

  const int tid  = threadIdx.x;
  const int lane = tid & 63;
  const int wave = tid >> 6;
  const int b    = blockIdx.x;

  {
    const float4* nf4 = (const float4*)(node + (size_t)b * NN * HH);
    float4* X4 = (float4*)&X[0][0];
    for (int i = tid; i < NN * HH / 4; i += 256) X4[i] = nf4[i];
    for (int i = tid; i < 2 * EE; i += 256) edg[i] = eidx[i];
    if (tid < HH) {
      biases[0][tid] = bm1[tid]; biases[1][tid] = bm2[tid];
      biases[2][tid] = bu1[tid]; biases[3][tid] = bu2[tid];
      biases[4][tid] = gamma_[tid]; biases[5][tid] = beta_[tid];
    }
  }
  __syncthreads();
  if (tid < 3 * NN) {
    const int t = tid % NN, ch = tid / NN;
    const int e0 = ch * 540, e1 = e0 + 540;
    int cnt = 0;
    for (int e = e0; e < e1; ++e) cnt += (edg[EE + e] == t);
    cnt3[ch][t] = cnt;
  }
  __syncthreads();
  if (tid == 0) {
    int run = 0;
    for (int t = 0; t < NN; ++t) {
      offs[t] = run;
      base3[0][t] = run;
      base3[1][t] = base3[0][t] + cnt3[0][t];
      base3[2][t] = base3[1][t] + cnt3[1][t];
      run = base3[2][t] + cnt3[2][t];
    }
    offs[NN] = run;
  }
  __syncthreads();
  if (tid < 3 * NN) {
    const int t = tid % NN, ch = tid / NN;
    const int e0 = ch * 540, e1 = e0 + 540;
    int pos = base3[ch][t];
    for (int e = e0; e < e1; ++e)
      if (edg[EE + e] == t) csr[pos++] = edg[e];
  }
  __syncthreads();

  const int c    = ((wave & 1) << 6) | lane;
  const int row0 = (wave >> 1) ? 41 : 0;
  const int nr   = (wave >> 1) ? 40 : 41;

  {
    float acc[41];
#pragma unroll
    for (int i = 0; i < 41; ++i) acc[i] = 0.f;
    gemm_acc_f32(X, Wm1, c, row0, nr, acc);
#pragma unroll
    for (int i = 0; i < 41; ++i) if (i < nr) Pb[row0 + i][c] = acc[i];
  }
  {
    float acc[41];
#pragma unroll
    for (int i = 0; i < 41; ++i) acc[i] = 0.f;
    gemm_acc_f32(X, Wm1 + HH * HH, c, row0, nr, acc);
#pragma unroll
    for (int i = 0; i < 41; ++i) if (i < nr) Qb[row0 + i][c] = acc[i];
  }
  __syncthreads();

  for (int t = wave; t < NN; t += 4) {
    const int o0 = offs[t], o1 = offs[t + 1];
    const float q0 = Qb[t][lane]      + biases[0][lane];
    const float q1 = Qb[t][lane + 64] + biases[0][lane + 64];
    float h0 = 0.f, h1 = 0.f;
    for (int e = o0; e < o1; ++e) {
      const int s = csr[e];
      h0 += fmaxf(Pb[s][lane]      + q0, 0.f);
      h1 += fmaxf(Pb[s][lane + 64] + q1, 0.f);
    }
    Qb[t][lane]      = h0;
    Qb[t][lane + 64] = h1;
  }
  __syncthreads();

  {
    float acc[41];
#pragma unroll
    for (int i = 0; i < 41; ++i) acc[i] = 0.f;
    gemm_acc_f32(Qb, Wm2, c, row0, nr, acc);
#pragma unroll
    for (int i = 0; i < 41; ++i) if (i < nr) {
      const int r = row0 + i;
      const float d = (float)(offs[r + 1] - offs[r]);
      Pb[r][c] = (acc[i] + d * biases[1][c]) * (1.f / fmaxf(d, 1.f));
    }
  }
  __syncthreads();

  {
    float acc[41];
#pragma unroll
    for (int i = 0; i < 41; ++i) acc[i] = 0.f;
    gemm_acc_f32(X,  Wu1,           c, row0, nr, acc);
    gemm_acc_f32(Pb, Wu1 + HH * HH, c, row0, nr, acc);
#pragma unroll
    for (int i = 0; i < 41; ++i) if (i < nr)
      Qb[row0 + i][c] = fmaxf(acc[i] + biases[2][c], 0.f);
  }
  __syncthreads();

  {
    float acc[41];
#pragma unroll
    for (int i = 0; i < 41; ++i) acc[i] = 0.f;
    gemm_acc_f32(Qb, Wu2, c, row0, nr, acc);
#pragma unroll
    for (int i = 0; i < 41; ++i) if (i < nr) {
      const int r = row0 + i;
      X[r][c] = X[r][c] + acc[i] + biases[3][c];
    }
  }
  __syncthreads();

  for (int r = wave; r < NN; r += 4) {
    const float x0 = X[r][lane], x1 = X[r][lane + 64];
    float s = x0 + x1;
#pragma unroll
    for (int off = 32; off; off >>= 1) s += __shfl_xor(s, off);
    const float mu = s * (1.f / 128.f);
    const float d0 = x0 - mu, d1 = x1 - mu;
    float v = d0 * d0 + d1 * d1;
#pragma unroll
    for (int off = 32; off; off >>= 1) v += __shfl_xor(v, off);
    const float rstd = rsqrtf(v * (1.f / 128.f) + 1e-5f);
    const size_t o = ((size_t)b * NN + r) * HH;
    out[o + lane]      = d0 * rstd * biases[4][lane]      + biases[5][lane];
    out[o + lane + 64] = d1 * rstd * biases[4][lane + 64] + biases[5][lane + 64];
  }
}

extern "C" void kernel_launch(void* const* d_in, const int* in_sizes, int n_in,
                              void* d_out, int out_size, void* d_ws, size_t ws_size,
                              hipStream_t stream) {
  (void)in_sizes; (void)n_in; (void)out_size;
  const float* node  = (const float*)d_in[0];
  const int*   eidx  = (const int*)  d_in[1];
  const float* Wm1   = (const float*)d_in[2];
  const float* bm1   = (const float*)d_in[3];
  const float* Wm2   = (const float*)d_in[4];
  const float* bm2   = (const float*)d_in[5];
  const float* Wu1   = (const float*)d_in[6];
  const float* bu1   = (const float*)d_in[7];
  const float* Wu2   = (const float*)d_in[8];
  const float* bu2   = (const float*)d_in[9];
  const float* gamma_= (const float*)d_in[10];
  const float* beta_ = (const float*)d_in[11];
  float* outp = (float*)d_out;

  if (ws_size >= (size_t)WS_NEED) {
    char* ws = (char*)d_ws;
    hipLaunchKernelGGL(setup_kernel, dim3(13), dim3(1024), 0, stream,
                       Wm1, Wm2, Wu1, Wu2, bm2, eidx, ws);
    hipLaunchKernelGGL(mpnn_fp16_kernel, dim3(256), dim3(1024), 0, stream,
                       node, bm1, bu1, bu2, gamma_, beta_, ws, outp);
  } else {
    hipLaunchKernelGGL(mpnn_fused_kernel, dim3(256), dim3(256), 0, stream,
                       node, eidx, Wm1, bm1, Wm2, bm2, Wu1, bu1, Wu2, bu2,
                       gamma_, beta_, outp);
  }
}

// Round 15
// 38.513 us; speedup vs baseline: 3.8951x; 1.0194x over previous
//
#include <hip/hip_runtime.h>

// Fused MPNN layer, B=256, N=81, H=128, E=1620 — MFMA fp16 two-kernel.
//   P = X @ Wm1[:H],  Q' = X @ Wm1[H:] + bm1
//   Hsum[t] = sum_{e: tgt=t} relu(P[src_e] + Q'[t])
//   Folded:  agg@Wu1b = (Hsum@Wc)*inv_deg + 1[deg>0]*bc,  Wc=Wm2@Wu1b, bc=bm2@Wu1b
//   h2 = relu(X@Wu1t + (Hsum@Wc)*inv + s*bc + bu1)
//   x  = X + h2 @ Wu2 + bu2 ;  out = LayerNorm(x)*gamma + beta
// Setup (grid 13 x 1024): blocks 0-7 pack weights to fp16 frag order; block 8
//   ballot-CSR (uchar); blocks 9-12 Wc + bc.
// Main (grid 256, 1024 thr = 16 waves): no fp32 X in LDS (residual re-read
//   from L2 in GEMM D; x held fp16 in bufQ for LN). LDS ~79 KB.

#define NN 81
#define HH 128
#define EE 1620
#define NCHK 26                         // ceil(EE/64)
#define MPAD 96
#define WB_BYTES 196608                 // 6 * 16384 ushorts (slot4 unused)
#define OFFS_OFF (WB_BYTES)             // int offs[82]
#define CSR_OFF  (OFFS_OFF + 82 * 4)    // uchar csr[1620] (padded to 1624)
#define BC_OFF   (CSR_OFF + 1624)       // float bc[128]
#define WS_NEED  (BC_OFF + HH * 4)

typedef _Float16 f16x8 __attribute__((ext_vector_type(8)));
typedef __fp16   h16x2 __attribute__((ext_vector_type(2)));
typedef __attribute__((ext_vector_type(8))) unsigned short ushort8v;
typedef __attribute__((ext_vector_type(4))) float f32x4;

__device__ __forceinline__ unsigned short f2h(float f) {
  union { _Float16 h; unsigned short u; } v; v.h = (_Float16)f; return v.u;
}
__device__ __forceinline__ float h2f(unsigned short u) {
  union { unsigned short u; _Float16 h; } v; v.u = u; return (float)v.h;
}
__device__ __forceinline__ unsigned f2h2(float x, float y) {   // v_cvt_pkrtz
  union { h16x2 h; unsigned u; } v;
  v.h = __builtin_amdgcn_cvt_pkrtz(x, y);
  return v.u;
}
__device__ __forceinline__ unsigned pk_add(unsigned a, unsigned b) {
  unsigned r; asm("v_pk_add_f16 %0, %1, %2" : "=v"(r) : "v"(a), "v"(b)); return r;
}
__device__ __forceinline__ unsigned pk_relu(unsigned a) {
  unsigned r; asm("v_pk_max_f16 %0, %1, %2" : "=v"(r) : "v"(a), "v"(0u)); return r;
}
__device__ __forceinline__ unsigned swzu(int r, int laneb) {
  return ((unsigned)(r * 256 + laneb)) ^ ((unsigned)((r & 7) << 4));
}

// ---------------- setup kernel ------------------------------------------------
__global__ __launch_bounds__(1024)
void setup_kernel(const float* __restrict__ Wm1, const float* __restrict__ Wm2,
                  const float* __restrict__ Wu1, const float* __restrict__ Wu2,
                  const float* __restrict__ bm2, const int* __restrict__ eidx,
                  char* __restrict__ ws) {
  __shared__ __align__(16) char arena[81920];
  const int tid = threadIdx.x;

  if (blockIdx.x < 8) {
    // pack 4 source mats to fp16 frag order: 4 mats * 8 nt * 4 ks * 64 lanes
    const int gid = blockIdx.x * 1024 + tid;
    const int lane = gid & 63;
    const int t = gid >> 6;
    const int ks = t & 3, nt = (t >> 2) & 7, mat = t >> 5;
    const float* src;
    int slot;
    if (mat == 0)      { src = Wm1;           slot = 0; }
    else if (mat == 1) { src = Wm1 + HH * HH; slot = 1; }
    else if (mat == 2) { src = Wu1;           slot = 3; }
    else               { src = Wu2;           slot = 5; }
    const int c = nt * 16 + (lane & 15);
    const int k0 = ks * 32 + (lane >> 4) * 8;
    f16x8 pv;
#pragma unroll
    for (int j = 0; j < 8; ++j) pv[j] = (_Float16)src[(k0 + j) * HH + c];
    *(f16x8*)((unsigned short*)ws + (size_t)slot * 16384 + (((nt * 4 + ks) * 64) + lane) * 8) = pv;
    return;
  }

  if (blockIdx.x == 8) {
    // deterministic CSR via ballot match-masks (stable counting sort), uchar out
    int* srcE  = (int*)arena;            // EE
    int* tgtE  = srcE + EE;              // EE
    int* rankS = tgtE + EE;              // EE
    int* cntC  = rankS + EE;             // NCHK*NN
    int* tot   = cntC + NCHK * NN;       // NN
    int* scanS = tot + NN;               // 128
    int* wsumS = scanS + 128;            // 2
    int* offsS = wsumS + 2;              // NN+1
    for (int i = tid; i < NCHK * NN; i += 1024) cntC[i] = 0;
    for (int i = tid; i < 2 * EE; i += 1024) srcE[i] = eidx[i];
    __syncthreads();
    const int lane = tid & 63, wv = tid >> 6;
    for (int c = wv; c < NCHK; c += 16) {
      const int e = c * 64 + lane;
      const bool ok = (e < EE);
      const int t = ok ? tgtE[e] : -1;
      unsigned long long mymask = 0;
#pragma unroll
      for (int i = 0; i < 64; ++i) {
        const int ti = __shfl(t, i);
        const unsigned long long bal = __ballot(t == ti);
        if (i == lane) mymask = bal;
      }
      if (ok) {
        const int rank = __popcll(mymask & ((1ull << lane) - 1ull));
        rankS[e] = rank;
        if (rank == 0) cntC[c * NN + t] = __popcll(mymask);
      }
    }
    __syncthreads();
    if (tid < NN) {
      int s = 0;
#pragma unroll
      for (int c = 0; c < NCHK; ++c) s += cntC[c * NN + tid];
      tot[tid] = s;
    }
    __syncthreads();
    if (tid < 128) {
      const int l = tid & 63, w = tid >> 6;
      int inc = (tid < NN) ? tot[tid] : 0;
#pragma unroll
      for (int d = 1; d < 64; d <<= 1) {
        int u = __shfl_up(inc, d);
        if (l >= d) inc += u;
      }
      scanS[tid] = inc;
      if (l == 63) wsumS[w] = inc;
    }
    __syncthreads();
    if (tid < 128) {
      const int w = tid >> 6;
      const int inc = scanS[tid] + (w ? wsumS[0] : 0);
      if (tid < NN) offsS[tid] = inc - tot[tid];
      if (tid == NN - 1) offsS[NN] = inc;
    }
    __syncthreads();
    if (tid < NN) {
      int run = offsS[tid];
#pragma unroll
      for (int c = 0; c < NCHK; ++c) {
        const int tmp = cntC[c * NN + tid];
        cntC[c * NN + tid] = run;
        run += tmp;
      }
    }
    __syncthreads();
    int* wofs = (int*)(ws + OFFS_OFF);
    unsigned char* wcsr = (unsigned char*)(ws + CSR_OFF);
    for (int i = tid; i <= NN; i += 1024) wofs[i] = offsS[i];
    for (int e = tid; e < EE; e += 1024) {
      const int t = tgtE[e];
      wcsr[cntC[(e >> 6) * NN + t] + rankS[e]] = (unsigned char)srcE[e];
    }
    return;
  }

  // blocks 9-12: Wc = Wm2 @ Wu1b, rows [32*bs,32*bs+32); pack slot 2; bs0: bc
  {
    const int bs = blockIdx.x - 9;
    float* WuL = (float*)arena;
    float* WmL = WuL + HH * HH;
    const float* Wu1b = Wu1 + HH * HH;
    float4* WuL4 = (float4*)WuL;
    const float4* src4 = (const float4*)Wu1b;
    for (int i = tid; i < HH * HH / 4; i += 1024) WuL4[i] = src4[i];
    const float4* wm4 = (const float4*)(Wm2 + bs * 32 * HH);
    float4* WmL4 = (float4*)WmL;
    if (tid < 32 * HH / 4) WmL4[tid] = wm4[tid];
    __syncthreads();
    const int kk = tid >> 5;
    const int k  = bs * 32 + kk;
    const int cg = tid & 31;
    f32x4 acc = (f32x4)0.f;
    for (int j = 0; j < HH; ++j) {
      const float a = WmL[kk * HH + j];
      const float4 w = WuL4[j * 32 + cg];
      acc[0] += a * w.x; acc[1] += a * w.y; acc[2] += a * w.z; acc[3] += a * w.w;
    }
    unsigned short* dst = (unsigned short*)ws;
#pragma unroll
    for (int q = 0; q < 4; ++q) {
      const int c = cg * 4 + q;
      const int nt = c >> 4;
      const int l = (((k & 31) >> 3) << 4) | (c & 15);
      dst[(size_t)2 * 16384 + (((nt * 4 + bs) * 64) + l) * 8 + (k & 7)] = f2h(acc[q]);
    }
    if (bs == 0 && tid < HH) {
      float s = 0.f;
      for (int j = 0; j < HH; ++j) s += bm2[j] * WuL[j * HH + tid];
      ((float*)(ws + BC_OFF))[tid] = s;
    }
  }
}

// ---------------- MFMA helpers (fp16, per wave: 3 M-tiles x 1 N-tile) --------
__device__ __forceinline__ void loadB(const unsigned short* Wp, int nt0, int lane,
                                      f16x8 (&Bf)[4]) {
#pragma unroll
  for (int ks = 0; ks < 4; ++ks)
    Bf[ks] = *(const f16x8*)(Wp + ((nt0 * 4 + ks) * 64 + lane) * 8);
}

__device__ __forceinline__ void gemm3(const char* Ab, const f16x8 (&Bf)[4],
                                      int lane, int mt0, f32x4 (&acc)[3]) {
  const int rl = lane & 15;
  const int kb = (lane >> 4) * 16;
  const unsigned swz = (unsigned)((rl & 7) << 4);
#pragma unroll
  for (int ks = 0; ks < 4; ++ks)
#pragma unroll
    for (int mm = 0; mm < 3; ++mm) {
      const int r = (mt0 + mm) * 16 + rl;
      const unsigned byte = (unsigned)(r * 256) + (((unsigned)(ks * 64 + kb)) ^ swz);
      f16x8 a = *(const f16x8*)(Ab + byte);
      acc[mm] = __builtin_amdgcn_mfma_f32_16x16x32_f16(a, Bf[ks], acc[mm], 0, 0, 0);
    }
}

__device__ __forceinline__ void gemm3x2(const char* Ab,
                                        const f16x8 (&B0)[4], const f16x8 (&B1)[4],
                                        int lane, int mt0,
                                        f32x4 (&a0)[3], f32x4 (&a1)[3]) {
  const int rl = lane & 15;
  const int kb = (lane >> 4) * 16;
  const unsigned swz = (unsigned)((rl & 7) << 4);
#pragma unroll
  for (int ks = 0; ks < 4; ++ks)
#pragma unroll
    for (int mm = 0; mm < 3; ++mm) {
      const int r = (mt0 + mm) * 16 + rl;
      const unsigned byte = (unsigned)(r * 256) + (((unsigned)(ks * 64 + kb)) ^ swz);
      f16x8 a = *(const f16x8*)(Ab + byte);
      a0[mm] = __builtin_amdgcn_mfma_f32_16x16x32_f16(a, B0[ks], a0[mm], 0, 0, 0);
      a1[mm] = __builtin_amdgcn_mfma_f32_16x16x32_f16(a, B1[ks], a1[mm], 0, 0, 0);
    }
}

__device__ __forceinline__ void gemm3_2A(const char* A0, const char* A1,
                                         const f16x8 (&B0)[4], const f16x8 (&B1)[4],
                                         int lane, int mt0,
                                         f32x4 (&a0)[3], f32x4 (&a1)[3]) {
  const int rl = lane & 15;
  const int kb = (lane >> 4) * 16;
  const unsigned swz = (unsigned)((rl & 7) << 4);
#pragma unroll
  for (int ks = 0; ks < 4; ++ks)
#pragma unroll
    for (int mm = 0; mm < 3; ++mm) {
      const int r = (mt0 + mm) * 16 + rl;
      const unsigned byte = (unsigned)(r * 256) + (((unsigned)(ks * 64 + kb)) ^ swz);
      f16x8 x0 = *(const f16x8*)(A0 + byte);
      a0[mm] = __builtin_amdgcn_mfma_f32_16x16x32_f16(x0, B0[ks], a0[mm], 0, 0, 0);
      f16x8 x1 = *(const f16x8*)(A1 + byte);
      a1[mm] = __builtin_amdgcn_mfma_f32_16x16x32_f16(x1, B1[ks], a1[mm], 0, 0, 0);
    }
}

__global__ __launch_bounds__(1024)
void mpnn_fp16_kernel(const float* __restrict__ node,
                      const float* __restrict__ bm1,
                      const float* __restrict__ bu1, const float* __restrict__ bu2,
                      const float* __restrict__ gamma_, const float* __restrict__ beta_,
                      const char* __restrict__ ws,
                      float* __restrict__ out) {
  __shared__ unsigned short XbS[MPAD * HH];   // swizzled fp16
  __shared__ unsigned short bufPS[MPAD * HH]; // P -> h2
  __shared__ unsigned short bufQS[MPAD * HH]; // Q' -> Hsum -> x(fp16)
  __shared__ __align__(4) unsigned char csrL[1624];   // uchar CSR
  __shared__ int   offsL[NN + 1];
  __shared__ float bias[6][HH];               // bm1,bc,bu1,bu2,gamma,beta
  char* Xb   = (char*)XbS;
  char* bufP = (char*)bufPS;
  char* bufQ = (char*)bufQS;

  const int tid  = threadIdx.x;
  const int lane = tid & 63;
  const int wave = tid >> 6;     // 0..15
  const int b    = blockIdx.x;

  const unsigned short* wpk = (const unsigned short*)ws;
  const int* wofs = (const int*)(ws + OFFS_OFF);
  const unsigned* wcsr4 = (const unsigned*)(ws + CSR_OFF);
  const float* wbc = (const float*)(ws + BC_OFF);

  // wave tile map: 16 waves = 8 N-tiles x 2 M-halves (3 M-tiles each)
  const int nt0 = wave & 7;
  const int mt0 = 3 * (wave >> 3);
  const int erow = (lane >> 4) * 4;
  const int ecol = lane & 15;
  const int C    = nt0 * 16 + ecol;

  // ---- GEMM-A B-frag preload (global, independent of LDS staging) ----
  f16x8 BA0[4], BA1[4];
  loadB(wpk, nt0, lane, BA0);
  loadB(wpk + 16384, nt0, lane, BA1);

  // ---- stage: Xb fp16 only (swizzled), csr/offs, biases ----
  {
    const float4* nf4 = (const float4*)(node + (size_t)b * NN * HH);
    const int i2 = tid + 2048;
    const bool has2 = (i2 < NN * HH / 4);     // 2592 float4 total
    float4 v0 = nf4[tid];
    float4 v1 = nf4[tid + 1024];
    float4 v2 = has2 ? nf4[i2] : make_float4(0.f, 0.f, 0.f, 0.f);
#pragma unroll
    for (int k = 0; k < 3; ++k) {
      const int i = tid + k * 1024;
      if (k == 2 && !has2) break;
      const float4 v = (k == 0) ? v0 : (k == 1) ? v1 : v2;
      const int r = i >> 5, c = (i & 31) * 4;
      uint2 pv; pv.x = f2h2(v.x, v.y); pv.y = f2h2(v.z, v.w);
      *(uint2*)(Xb + swzu(r, c * 2)) = pv;
    }
    if (tid < (MPAD - NN) * 16) {   // zero pad rows 81..95
      const int r = NN + tid / 16, m = tid % 16;
      ushort8v z = {0,0,0,0,0,0,0,0};
      *(ushort8v*)(Xb + swzu(r, m * 16)) = z;
    }
    if (tid < 406) ((unsigned*)csrL)[tid] = wcsr4[tid];   // 1624 B as 406 uints
    if (tid < NN + 1) offsL[tid] = wofs[tid];
    if (tid < HH) {
      bias[0][tid] = bm1[tid];  bias[1][tid] = wbc[tid];
      bias[2][tid] = bu1[tid];  bias[3][tid] = bu2[tid];
      bias[4][tid] = gamma_[tid]; bias[5][tid] = beta_[tid];
    }
  }
  __syncthreads();

  // ---- GEMM A: P = Xb@Wm1t -> bufP ; Q' = Xb@Wm1b + bm1 -> bufQ ----
  {
    f32x4 accP[3], accQ[3];
#pragma unroll
    for (int mm = 0; mm < 3; ++mm) { accP[mm] = (f32x4)0.f; accQ[mm] = (f32x4)0.f; }
    gemm3x2(Xb, BA0, BA1, lane, mt0, accP, accQ);
#pragma unroll
    for (int mm = 0; mm < 3; ++mm)
#pragma unroll
      for (int rg = 0; rg < 4; ++rg) {
        const int R = (mt0 + mm) * 16 + erow + rg;
        const unsigned byte = swzu(R, C * 2);
        const bool ok = (R < NN);
        *(unsigned short*)(bufP + byte) = ok ? f2h(accP[mm][rg]) : (unsigned short)0;
        *(unsigned short*)(bufQ + byte) = ok ? f2h(accQ[mm][rg] + bias[0][C]) : (unsigned short)0;
      }
  }
  __syncthreads();

  // ---- edge aggregation, packed fp16, uchar CSR (4 idx per load) ----
  {
    const int lb = lane * 4;
    for (int t = wave; t < NN; t += 16) {
      const unsigned qbyte = swzu(t, lb);
      const unsigned q = *(const unsigned*)(bufQ + qbyte);
      unsigned h = 0u, g = 0u;
      int e = offsL[t];
      const int o1 = offsL[t + 1];
      for (; e < o1 && (e & 3); ++e) {
        const int s = csrL[e];
        const unsigned pp = *(const unsigned*)(bufP + swzu(s, lb));
        h = pk_add(h, pk_relu(pk_add(pp, q)));
      }
      for (; e + 4 <= o1; e += 4) {
        const unsigned cw = *(const unsigned*)(csrL + e);
        const int s0 = cw & 0xff, s1 = (cw >> 8) & 0xff;
        const int s2 = (cw >> 16) & 0xff, s3 = cw >> 24;
        const unsigned p0 = *(const unsigned*)(bufP + swzu(s0, lb));
        const unsigned p1 = *(const unsigned*)(bufP + swzu(s1, lb));
        const unsigned p2 = *(const unsigned*)(bufP + swzu(s2, lb));
        const unsigned p3 = *(const unsigned*)(bufP + swzu(s3, lb));
        h = pk_add(h, pk_relu(pk_add(p0, q)));
        g = pk_add(g, pk_relu(pk_add(p1, q)));
        h = pk_add(h, pk_relu(pk_add(p2, q)));
        g = pk_add(g, pk_relu(pk_add(p3, q)));
      }
      for (; e < o1; ++e) {
        const int s = csrL[e];
        const unsigned pp = *(const unsigned*)(bufP + swzu(s, lb));
        h = pk_add(h, pk_relu(pk_add(pp, q)));
      }
      h = pk_add(h, g);
      *(unsigned*)(bufQ + qbyte) = h;
    }
  }
  __syncthreads();

  // ---- GEMM BC: T = Hsum@Wc ; U = Xb@Wu1t ;
  //      h2 = relu(U + T*inv_deg + s*bc + bu1) -> bufP ----
  {
    f16x8 BW[4], BU[4];
    loadB(wpk + 2 * 16384, nt0, lane, BW);
    loadB(wpk + 3 * 16384, nt0, lane, BU);
    f32x4 accT[3], accU[3];
#pragma unroll
    for (int mm = 0; mm < 3; ++mm) { accT[mm] = (f32x4)0.f; accU[mm] = (f32x4)0.f; }
    gemm3_2A(bufQ, Xb, BW, BU, lane, mt0, accT, accU);
#pragma unroll
    for (int mm = 0; mm < 3; ++mm)
#pragma unroll
      for (int rg = 0; rg < 4; ++rg) {
        const int R = (mt0 + mm) * 16 + erow + rg;
        float v = 0.f;
        if (R < NN) {
          const int dg = offsL[R + 1] - offsL[R];
          const float inv = (dg > 0) ? 1.f / (float)dg : 1.f;
          const float sf  = (dg > 0) ? 1.f : 0.f;
          v = fmaxf(accU[mm][rg] + accT[mm][rg] * inv + sf * bias[1][C] + bias[2][C], 0.f);
        }
        *(unsigned short*)(bufP + swzu(R, C * 2)) = f2h(v);
      }
  }
  __syncthreads();

  // ---- GEMM D: x = resid + h2@Wu2 + bu2 -> bufQ (fp16, swizzled) ----
  {
    f16x8 BD[4];
    loadB(wpk + 5 * 16384, nt0, lane, BD);
    // residual loads issued before MFMAs (L2-hot from the stage pass)
    const float* nodeB = node + (size_t)b * NN * HH;
    float resid[3][4];
#pragma unroll
    for (int mm = 0; mm < 3; ++mm)
#pragma unroll
      for (int rg = 0; rg < 4; ++rg) {
        const int R = (mt0 + mm) * 16 + erow + rg;
        resid[mm][rg] = (R < NN) ? nodeB[R * HH + C] : 0.f;
      }
    f32x4 acc[3];
#pragma unroll
    for (int mm = 0; mm < 3; ++mm) acc[mm] = (f32x4)0.f;
    gemm3(bufP, BD, lane, mt0, acc);
#pragma unroll
    for (int mm = 0; mm < 3; ++mm)
#pragma unroll
      for (int rg = 0; rg < 4; ++rg) {
        const int R = (mt0 + mm) * 16 + erow + rg;
        if (R < NN) {
          const float x = resid[mm][rg] + acc[mm][rg] + bias[3][C];
          *(unsigned short*)(bufQ + swzu(R, C * 2)) = f2h(x);
        }
      }
  }
  __syncthreads();

  // ---- LayerNorm per row (x from bufQ fp16) + store ----
  for (int r = wave; r < NN; r += 16) {
    const float x0 = h2f(*(const unsigned short*)(bufQ + swzu(r, lane * 2)));
    const float x1 = h2f(*(const unsigned short*)(bufQ + swzu(r, (lane + 64) * 2)));
    float s = x0 + x1;
#pragma unroll
    for (int off = 32; off; off >>= 1) s += __shfl_xor(s, off);
    const float mu = s * (1.f / 128.f);
    const float d0 = x0 - mu, d1 = x1 - mu;
    float v = d0 * d0 + d1 * d1;
#pragma unroll
    for (int off = 32; off; off >>= 1) v += __shfl_xor(v, off);
    const float rstd = rsqrtf(v * (1.f / 128.f) + 1e-5f);
    const size_t o = ((size_t)b * NN + r) * HH;
    out[o + lane]      = d0 * rstd * bias[4][lane]      + bias[5][lane];
    out[o + lane + 64] = d1 * rstd * bias[4][lane + 64] + bias[5][lane + 64];
  }
}

// ================= fp32 fallback (known-good, used only if ws too small) =====
__device__ __forceinline__ void gemm_acc_f32(const float (*A)[HH], const float* __restrict__ Wg,
                                             int c, int row0, int nr, float (&acc)[41]) {
  float w[8];
#pragma unroll
  for (int j = 0; j < 8; ++j) w[j] = Wg[j * HH + c];
  for (int k0 = 0; k0 < HH; k0 += 8) {
    float wn[8];
    if (k0 + 8 < HH) {
#pragma unroll
      for (int j = 0; j < 8; ++j) wn[j] = Wg[(k0 + 8 + j) * HH + c];
    }
#pragma unroll
    for (int i = 0; i < 41; ++i) {
      if (i < nr) {
        const float4 a0 = *(const float4*)&A[row0 + i][k0];
        const float4 a1 = *(const float4*)&A[row0 + i][k0 + 4];
        acc[i] += a0.x * w[0] + a0.y * w[1] + a0.z * w[2] + a0.w * w[3]
                + a1.x * w[4] + a1.y * w[5] + a1.z * w[6] + a1.w * w[7];
      }
    }
#pragma unroll
    for (int j = 0; j < 8; ++j) w[j] = wn[j];
  }
}

__global__ __launch_bounds__(256, 1)
void mpnn_fused_kernel(const float* __restrict__ node, const int* __restrict__ eidx,
                       const float* __restrict__ Wm1, const float* __restrict__ bm1,
                       const float* __restrict__ Wm2, const float* __restrict__ bm2,
                       const float* __restrict__ Wu1, const float* __restrict__ bu1,
                       const float* __restrict__ Wu2, const float* __restrict__ bu2,
                       const float* __restrict__ gamma_, const float* __restrict__ beta_,
                       float* __restrict__ out) {
  __shared__ float X[NN][HH];
  __shared__ float Pb[NN][HH];
  __shared__ float Qb[NN][HH];
  __shared__ int   edg[2 * EE];
  __shared__ int   csr[EE];
  __shared__ int   offs[NN + 1];
  __shared__ int   cnt3[3][NN];
  __shared__ int   base3[3][NN];
  __shared__ float biases[6][HH];

  const int tid  = threadIdx.x;
  const int lane = tid & 63;
  const int wave = tid >> 6;
  const int b    = blockIdx.x;

  {
    const float4* nf4 = (const float4*)(node + (size_t)b * NN * HH);
    float4* X4 = (float4*)&X[0][0];
    for (int i = tid; i < NN * HH / 4; i += 256) X4[i] = nf4[i];
    for (int i = tid; i < 2 * EE; i += 256) edg[i] = eidx[i];
    if (tid < HH) {
      biases[0][tid] = bm1[tid]; biases[1][tid] = bm2[tid];
      biases[2][tid] = bu1[tid]; biases[3][tid] = bu2[tid];
      biases[4][tid] = gamma_[tid]; biases[5][tid] = beta_[tid];
    }
  }
  __syncthreads();
  if (tid < 3 * NN) {
    const int t = tid % NN, ch = tid / NN;
    const int e0 = ch * 540, e1 = e0 + 540;
    int cnt = 0;
    for (int e = e0; e < e1; ++e) cnt += (edg[EE + e] == t);
    cnt3[ch][t] = cnt;
  }
  __syncthreads();
  if (tid == 0) {
    int run = 0;
    for (int t = 0; t < NN; ++t) {
      offs[t] = run;
      base3[0][t] = run;
      base3[1][t] = base3[0][t] + cnt3[0][t];
      base3[2][t] = base3[1][t] + cnt3[1][t];
      run = base3[2][t] + cnt3[2][t];
    }
    offs[NN] = run;
  }
  __syncthreads();
  if (tid < 3 * NN) {
    const int t = tid % NN, ch = tid / NN;
    const int e0 = ch * 540, e1 = e0 + 540;
    int pos = base3[ch][t];
    for (int e = e0; e < e1; ++e)
      if (edg[EE + e] == t) csr[pos++] = edg[e];
  }
  __syncthreads();

  const int c    = ((wave & 1) << 6) | lane;
  const int row0 = (wave >> 1) ? 41 : 0;
  const int nr   = (wave >> 1) ? 40 : 41;

  {
    float acc[41];
#pragma unroll
    for (int i = 0; i < 41; ++i) acc[i] = 0.f;
    gemm_acc_f32(X, Wm1, c, row0, nr, acc);
#pragma unroll
    for (int i = 0; i < 41; ++i) if (i < nr) Pb[row0 + i][c] = acc[i];
  }
  {
    float acc[41];
#pragma unroll
    for (int i = 0; i < 41; ++i) acc[i] = 0.f;
    gemm_acc_f32(X, Wm1 + HH * HH, c, row0, nr, acc);
#pragma unroll
    for (int i = 0; i < 41; ++i) if (i < nr) Qb[row0 + i][c] = acc[i];
  }
  __syncthreads();

  for (int t = wave; t < NN; t += 4) {
    const int o0 = offs[t], o1 = offs[t + 1];
    const float q0 = Qb[t][lane]      + biases[0][lane];
    const float q1 = Qb[t][lane + 64] + biases[0][lane + 64];
    float h0 = 0.f, h1 = 0.f;
    for (int e = o0; e < o1; ++e) {
      const int s = csr[e];
      h0 += fmaxf(Pb[s][lane]      + q0, 0.f);
      h1 += fmaxf(Pb[s][lane + 64] + q1, 0.f);
    }
    Qb[t][lane]      = h0;
    Qb[t][lane + 64] = h1;
  }
  __syncthreads();

  {
    float acc[41];
#pragma unroll
    for (int i = 0; i < 41; ++i) acc[i] = 0.f;
    gemm_acc_f32(Qb, Wm2, c, row0, nr, acc);
#pragma unroll
    for (int i = 0; i < 41; ++i) if (i < nr) {
      const int r = row0 + i;
      const float d = (float)(offs[r + 1] - offs[r]);
      Pb[r][c] = (acc[i] + d * biases[1][c]) * (1.f / fmaxf(d, 1.f));
    }
  }
  __syncthreads();

  {
    float acc[41];
#pragma unroll
    for (int i = 0; i < 41; ++i) acc[i] = 0.f;
    gemm_acc_f32(X,  Wu1,           c, row0, nr, acc);
    gemm_acc_f32(Pb, Wu1 + HH * HH, c, row0, nr, acc);
#pragma unroll
    for (int i = 0; i < 41; ++i) if (i < nr)
      Qb[row0 + i][c] = fmaxf(acc[i] + biases[2][c], 0.f);
  }
  __syncthreads();

  {
    float acc[41];
#pragma unroll
    for (int i = 0; i < 41; ++i) acc[i] = 0.f;
    gemm_acc_f32(Qb, Wu2, c, row0, nr, acc);
#pragma unroll
    for (int i = 0; i < 41; ++i) if (i < nr) {
      const int r = row0 + i;
      X[r][c] = X[r][c] + acc[i] + biases[3][c];
    }
  }
  __syncthreads();

  for (int r = wave; r < NN; r += 4) {
    const float x0 = X[r][lane], x1 = X[r][lane + 64];
    float s = x0 + x1;
#pragma unroll
    for (int off = 32; off; off >>= 1) s += __shfl_xor(s, off);
    const float mu = s * (1.f / 128.f);
    const float d0 = x0 - mu, d1 = x1 - mu;
    float v = d0 * d0 + d1 * d1;
#pragma unroll
    for (int off = 32; off; off >>= 1) v += __shfl_xor(v, off);
    const float rstd = rsqrtf(v * (1.f / 128.f) + 1e-5f);
    const size_t o = ((size_t)b * NN + r) * HH;
    out[o + lane]      = d0 * rstd * biases[4][lane]      + biases[5][lane];
    out[o + lane + 64] = d1 * rstd * biases[4][lane + 64] + biases[5][lane + 64];
  }
}

extern "C" void kernel_launch(void* const* d_in, const int* in_sizes, int n_in,
                              void* d_out, int out_size, void* d_ws, size_t ws_size,
                              hipStream_t stream) {
  (void)in_sizes; (void)n_in; (void)out_size;
  const float* node  = (const float*)d_in[0];
  const int*   eidx  = (const int*)  d_in[1];
  const float* Wm1   = (const float*)d_in[2];
  const float* bm1   = (const float*)d_in[3];
  const float* Wm2   = (const float*)d_in[4];
  const float* bm2   = (const float*)d_in[5];
  const float* Wu1   = (const float*)d_in[6];
  const float* bu1   = (const float*)d_in[7];
  const float* Wu2   = (const float*)d_in[8];
  const float* bu2   = (const float*)d_in[9];
  const float* gamma_= (const float*)d_in[10];
  const float* beta_ = (const float*)d_in[11];
  float* outp = (float*)d_out;

  if (ws_size >= (size_t)WS_NEED) {
    char* ws = (char*)d_ws;
    hipLaunchKernelGGL(setup_kernel, dim3(13), dim3(1024), 0, stream,
                       Wm1, Wm2, Wu1, Wu2, bm2, eidx, ws);
    hipLaunchKernelGGL(mpnn_fp16_kernel, dim3(256), dim3(1024), 0, stream,
                       node, bm1, bu1, bu2, gamma_, beta_, ws, outp);
  } else {
    hipLaunchKernelGGL(mpnn_fused_kernel, dim3(256), dim3(256), 0, stream,
                       node, eidx, Wm1, bm1, Wm2, bm2, Wu1, bu1, Wu2, bu2,
                       gamma_, beta_, outp);
  }
}